// Round 11
// baseline (398.492 us; speedup 1.0000x reference)
//
#include <hip/hip_runtime.h>
#include <hip/hip_bf16.h>
#include <stdint.h>

// DynamicSparseAttention MI355X r19 — fp32 I/O.
// History: r9 @322 (attn 148). r10/r16 spill fails. r11-r13 block-config
// fails (occupancy pinned ~14 waves/CU). r14 @317.3 (wave-independent tail,
// 1 barrier). r15 ILP x. r17 @313.9 (attn 137.3): +s_setprio T5 (-5.5us).
// r18 @313.8: GEMM XCD swizzle + PV-32 both neutral (kept, harmless).
// r19: selection rank loop C(runtime) -> fixed-64 unrolled with -FLT_MAX
// prefill: the runtime-bound loop serialized C x ~120cyc LDS-broadcast
// latency per query (compiler can't unroll/pipeline it); fixed 64 issues all
// 128 broadcast reads back-to-back. Selection result bit-identical (junk
// slots = -FLT_MAX never out-rank real candidates; take still needs lane<C).
// gemm_qk / gemm_nl2 / presplit unchanged from r18.

typedef __bf16 bf16_t;
typedef bf16_t bf16x8 __attribute__((ext_vector_type(8)));
typedef bf16_t bf16x4 __attribute__((ext_vector_type(4)));
typedef float  f32x4  __attribute__((ext_vector_type(4)));

#define NB 2
#define SS 1024
#define EE 1024
#define NH 16
#define HD 64
#define NBH (NB*NH)
#define NX_ ((size_t)NB*SS*EE)   // 2,097,152
#define NW_ ((size_t)EE*EE)      // 1,048,576

__device__ __forceinline__ f32x4 mfma16(bf16x8 a, bf16x8 b, f32x4 c) {
  return __builtin_amdgcn_mfma_f32_16x16x32_bf16(a, b, c, 0, 0, 0);
}

__device__ __forceinline__ void split3(float x, bf16_t& h, bf16_t& m, bf16_t& l) {
  h = (bf16_t)x;
  float r = x - (float)h;     // exact
  m = (bf16_t)r;
  float r2 = r - (float)m;    // exact
  l = (bf16_t)r2;             // residual <= 2^-27 |x|
}

// wave-local LDS ordering fence (per-wave scratch; no cross-wave deps)
__device__ __forceinline__ void wave_fence() {
  __builtin_amdgcn_wave_barrier();
  __builtin_amdgcn_s_waitcnt(0);
  __builtin_amdgcn_wave_barrier();
}

// async global->LDS, 16B per lane; LDS dest = wave-uniform base + lane*16
__device__ __forceinline__ void gld16(const bf16_t* g, bf16_t* l) {
  __builtin_amdgcn_global_load_lds(
      (const __attribute__((address_space(1))) void*)g,
      (__attribute__((address_space(3))) void*)l, 16, 0, 0);
}

// ---------------------------------------------------------------------------
// fused presplit of x, Wq, Wk, Wv, Wo into h/m/l limb arrays (unchanged)
// ---------------------------------------------------------------------------
__global__ __launch_bounds__(256) void presplit_all(
    const float* __restrict__ x,  const float* __restrict__ wq,
    const float* __restrict__ wk, const float* __restrict__ wv,
    const float* __restrict__ wo, bf16_t* __restrict__ base)
{
  const int blk = blockIdx.x;
  const float* src; bf16_t* h; size_t n; int i;
  if (blk < 2048)      { src = x;  h = base;                   n = NX_; i = blk;        }
  else if (blk < 3072) { src = wq; h = base + 3*NX_;           n = NW_; i = blk - 2048; }
  else if (blk < 4096) { src = wk; h = base + 3*NX_ + 3*NW_;   n = NW_; i = blk - 3072; }
  else if (blk < 5120) { src = wv; h = base + 3*NX_ + 6*NW_;   n = NW_; i = blk - 4096; }
  else                 { src = wo; h = base + 3*NX_ + 9*NW_;   n = NW_; i = blk - 5120; }
  bf16_t* m = h + n;
  bf16_t* l = m + n;
  int idx = i * 256 + threadIdx.x;            // float4 index
  float4 v = ((const float4*)src)[idx];
  float t[4] = { v.x, v.y, v.z, v.w };
  bf16x4 hv, mv, lv;
#pragma unroll
  for (int j = 0; j < 4; j++) {
    bf16_t a, b, c;
    split3(t[j], a, b, c);
    hv[j] = a; mv[j] = b; lv[j] = c;
  }
  ((bf16x4*)h)[idx] = hv;
  ((bf16x4*)m)[idx] = mv;
  ((bf16x4*)l)[idx] = lv;
}

// ---------------------------------------------------------------------------
// Fused Q+K projection GEMM, 128x64 tile. grid (16, 16, 2) = 512 blocks.
// XCD-contiguous swizzle (r18, neutral but harmless). Math unchanged.
// ---------------------------------------------------------------------------
__global__ __launch_bounds__(256, 2) void gemm_qk(
    const bf16_t* __restrict__ Ah, const bf16_t* __restrict__ Am,
    const bf16_t* __restrict__ Al,
    const bf16_t* __restrict__ Bqh, const bf16_t* __restrict__ Bqm,
    const bf16_t* __restrict__ Bql,
    const bf16_t* __restrict__ Bkh, const bf16_t* __restrict__ Bkm,
    const bf16_t* __restrict__ Bkl,
    const float* __restrict__ biasq, const float* __restrict__ biask,
    bf16_t* __restrict__ qH, bf16_t* __restrict__ qM, bf16_t* __restrict__ qL,
    bf16_t* __restrict__ kH, bf16_t* __restrict__ kM, bf16_t* __restrict__ kL)
{
  __shared__ bf16_t As[3][128 * 32];   // row-major, unpadded (gld16 lane order)
  __shared__ bf16_t Bs[3][64 * 32];

  // XCD-contiguous remap (bijective on [0,512); 512%8==0)
  const int flat = blockIdx.x + 16 * blockIdx.y + 256 * blockIdx.z;
  const int eff  = (flat & 7) * 64 + (flat >> 3);
  const int bx = eff & 15, by = (eff >> 4) & 15, z = eff >> 8;

  const bf16_t* AP[3] = { Ah, Am, Al };
  const bf16_t* BP[3] = { z ? Bkh : Bqh, z ? Bkm : Bqm, z ? Bkl : Bql };
  const float* bias = z ? biask : biasq;
  bf16_t* dH = z ? kH : qH;
  bf16_t* dM = z ? kM : qM;
  bf16_t* dL = z ? kL : qL;

  const int tid  = threadIdx.x;
  const int wv   = tid >> 6, lane = tid & 63;
  const int quad = lane >> 4, l16 = lane & 15;
  const int m0 = by * 128, n0 = bx * 64;
  const int wm = (wv & 1) * 64, wn = (wv >> 1) * 32;

  // staging: A rows [wv*32, wv*32+32) via two gld16; B rows [wv*16, wv*16+16)
  const int arow = wv * 32 + (lane >> 2);
  const int brow = wv * 16 + (lane >> 2);
  const int q8   = (lane & 3) * 8;
  const size_t aoff0 = (size_t)(m0 + arow) * 1024 + q8;
  const size_t boff  = (size_t)(n0 + brow) * 1024 + q8;

  f32x4 accH0[4][2] = {};   // hh, k < 512
  f32x4 accH1[4][2] = {};   // hh, k >= 512
  f32x4 accC [4][2] = {};   // corrections (small magnitude)

  for (int k0 = 0; k0 < 1024; k0 += 32) {
    __syncthreads();                     // previous iter's frags consumed
#pragma unroll
    for (int L = 0; L < 3; L++) {
      gld16(AP[L] + aoff0 + k0,              &As[L][(wv * 32) * 32]);
      gld16(AP[L] + aoff0 + 16 * 1024 + k0,  &As[L][(wv * 32 + 16) * 32]);
      gld16(BP[L] + boff + k0,               &Bs[L][(wv * 16) * 32]);
    }
    __syncthreads();                     // staging visible

    bf16x8 bfr[2][3];
#pragma unroll
    for (int nt = 0; nt < 2; nt++)
#pragma unroll
      for (int L = 0; L < 3; L++)
        bfr[nt][L] = *(const bf16x8*)&Bs[L][(wn + nt * 16 + l16) * 32 + quad * 8];

    const bool hi = (k0 >= 512);
#pragma unroll
    for (int mt = 0; mt < 4; mt++) {
      bf16x8 af[3];
#pragma unroll
      for (int L = 0; L < 3; L++)
        af[L] = *(const bf16x8*)&As[L][(wm + mt * 16 + l16) * 32 + quad * 8];
#pragma unroll
      for (int nt = 0; nt < 2; nt++) {
        f32x4& H = hi ? accH1[mt][nt] : accH0[mt][nt];
        H = mfma16(af[0], bfr[nt][0], H);                      // hh
        f32x4 c = accC[mt][nt];
        c = mfma16(af[0], bfr[nt][1], c);                      // hm
        c = mfma16(af[1], bfr[nt][0], c);                      // mh
        c = mfma16(af[0], bfr[nt][2], c);                      // hl
        c = mfma16(af[2], bfr[nt][0], c);                      // lh
        c = mfma16(af[1], bfr[nt][1], c);                      // mm
        accC[mt][nt] = c;
      }
    }
  }

  // epilogue: D[row=quad*4+r][col=l16] -> 3-way split limbs at [B,H,S,HD]
#pragma unroll
  for (int mt = 0; mt < 4; mt++)
#pragma unroll
  for (int nt = 0; nt < 2; nt++)
#pragma unroll
  for (int r  = 0; r  < 4;  r++) {
    int gm = m0 + wm + mt * 16 + quad * 4 + r;
    int gn = n0 + wn + nt * 16 + l16;
    float v = (accH0[mt][nt][r] + accH1[mt][nt][r]) + accC[mt][nt][r] + bias[gn];
    int b_ = gm >> 10, s_ = gm & 1023, h_ = gn >> 6, d_ = gn & 63;
    size_t di = (((size_t)b_ * NH + h_) * SS + s_) * HD + d_;
    bf16_t hh, mm, ll;
    split3(v, hh, mm, ll);
    dH[di] = hh; dM[di] = mm; dL[di] = ll;
  }
}

// ---------------------------------------------------------------------------
// 3-product NT GEMM (hh k-split + hm/mh corrections), 64x64 tile, grid (16,32).
// MODE 1: fp32 [B,H,S,HD] (v-proj).  MODE 2: fp32 row-major [M,N] (o-proj).
// XCD-contiguous swizzle (r18). Math unchanged.
// ---------------------------------------------------------------------------
template<int MODE>
__global__ __launch_bounds__(256, 4) void gemm_nl2(
    const bf16_t* __restrict__ Ah, const bf16_t* __restrict__ Am,
    const bf16_t* __restrict__ Bh, const bf16_t* __restrict__ Bm,
    const float* __restrict__ bias, float* __restrict__ dF)
{
  __shared__ bf16_t As[2][64 * 32];
  __shared__ bf16_t Bs[2][64 * 32];

  const bf16_t* AP[2] = { Ah, Am };
  const bf16_t* BP[2] = { Bh, Bm };

  // XCD-contiguous remap (bijective on [0,512))
  const int flat = blockIdx.x + 16 * blockIdx.y;
  const int eff  = (flat & 7) * 64 + (flat >> 3);
  const int bx = eff & 15, by = eff >> 4;

  const int tid  = threadIdx.x;
  const int wv   = tid >> 6, lane = tid & 63;
  const int quad = lane >> 4, l16 = lane & 15;
  const int m0 = by * 64, n0 = bx * 64;
  const int wm = (wv & 1) * 32, wn = (wv >> 1) * 32;

  const int srow = wv * 16 + (lane >> 2);
  const int q8   = (lane & 3) * 8;
  const size_t aoff = (size_t)(m0 + srow) * 1024 + q8;
  const size_t boff = (size_t)(n0 + srow) * 1024 + q8;

  f32x4 accH0[2][2] = {};
  f32x4 accH1[2][2] = {};
  f32x4 accC [2][2] = {};

  for (int k0 = 0; k0 < 1024; k0 += 32) {
    __syncthreads();
#pragma unroll
    for (int L = 0; L < 2; L++) {
      gld16(AP[L] + aoff + k0, &As[L][(wv * 16) * 32]);
      gld16(BP[L] + boff + k0, &Bs[L][(wv * 16) * 32]);
    }
    __syncthreads();

    bf16x8 bfr[2][2];
#pragma unroll
    for (int nt = 0; nt < 2; nt++)
#pragma unroll
      for (int L = 0; L < 2; L++)
        bfr[nt][L] = *(const bf16x8*)&Bs[L][(wn + nt * 16 + l16) * 32 + quad * 8];

    const bool hi = (k0 >= 512);
#pragma unroll
    for (int mt = 0; mt < 2; mt++) {
      bf16x8 af[2];
#pragma unroll
      for (int L = 0; L < 2; L++)
        af[L] = *(const bf16x8*)&As[L][(wm + mt * 16 + l16) * 32 + quad * 8];
#pragma unroll
      for (int nt = 0; nt < 2; nt++) {
        f32x4& H = hi ? accH1[mt][nt] : accH0[mt][nt];
        H = mfma16(af[0], bfr[nt][0], H);                      // hh
        f32x4 c = accC[mt][nt];
        c = mfma16(af[0], bfr[nt][1], c);                      // hm
        c = mfma16(af[1], bfr[nt][0], c);                      // mh
        accC[mt][nt] = c;
      }
    }
  }

#pragma unroll
  for (int mt = 0; mt < 2; mt++)
#pragma unroll
  for (int nt = 0; nt < 2; nt++)
#pragma unroll
  for (int r  = 0; r  < 4;  r++) {
    int gm = m0 + wm + mt * 16 + quad * 4 + r;
    int gn = n0 + wn + nt * 16 + l16;
    float v = (accH0[mt][nt][r] + accH1[mt][nt][r]) + accC[mt][nt][r] + bias[gn];
    if (MODE == 2) {
      dF[(size_t)gm * 1024 + gn] = v;
    } else {
      int b_ = gm >> 10, s_ = gm & 1023, h_ = gn >> 6, d_ = gn & 63;
      dF[(((size_t)b_ * NH + h_) * SS + s_) * HD + d_] = v;
    }
  }
}

// ---------------------------------------------------------------------------
// Fused attention r19 (= r18 + fixed-64 rank loop): one (b,h) x 16 queries,
// 512 thr / 8 waves. Score phase: single-chunk 16x1028 transpose, wave wv
// covers keys [wv*128,+128), r9-exact accumulation, s_setprio(1) around each
// t2's 12-MFMA cluster. ONE block barrier. Tail wave-independent: wave wv
// owns queries 2wv, 2wv+1; bins in sc row 2wv, selW/selI in row 2wv+1.
// Rank: candV prefilled -FLT_MAX -> compile-time 64-iter unrolled loop
// (128 pipelined broadcast reads instead of C serial latency-bound ones).
// PV wave-local, 32-deep batched gather.
// ---------------------------------------------------------------------------
__global__ __launch_bounds__(512, 4) void attn_topk(
    const bf16_t* __restrict__ qhg, const bf16_t* __restrict__ qmg,
    const bf16_t* __restrict__ qlg,
    const bf16_t* __restrict__ khg, const bf16_t* __restrict__ kmg,
    const bf16_t* __restrict__ klg,
    const float*  __restrict__ vg,
    bf16_t* __restrict__ attnH, bf16_t* __restrict__ attnM)
{
  __shared__ float sc[16 * 1028];       // scores; rows become per-wave scratch

  const int tid  = threadIdx.x;
  const int wv   = tid >> 6, lane = tid & 63;
  const int quad = lane >> 4, l16 = lane & 15;
  const int xcd = blockIdx.x & 7;
  const int g   = blockIdx.x >> 3;        // 0..255
  const int bh  = xcd + 8 * (g >> 6);     // 0..31 (bh pinned to XCD)
  const int qt  = g & 63;
  const int b_ = bh >> 4, h_ = bh & 15;
  const int q0 = qt * 16;

  // A-frags direct from global: lane holds q[m=l16][k=quad*8+j]
  const size_t qbase = ((size_t)bh * SS + q0 + l16) * HD + quad * 8;
  bf16x8 aH[2], aM[2], aL[2];
#pragma unroll
  for (int ks = 0; ks < 2; ks++) {
    aH[ks] = *(const bf16x8*)(qhg + qbase + ks * 32);
    aM[ks] = *(const bf16x8*)(qmg + qbase + ks * 32);
    aL[ks] = *(const bf16x8*)(qlg + qbase + ks * 32);
  }

  // ---- score phase: wave wv covers keys [wv*128, wv*128+128) — r9-exact ----
  const size_t kwb = ((size_t)bh * SS + wv * 128 + l16) * HD + quad * 8;
#pragma unroll 4
  for (int t2 = 0; t2 < 8; t2++) {
    const size_t kb = kwb + (size_t)t2 * 16 * HD;
    bf16x8 bH0 = *(const bf16x8*)(khg + kb);
    bf16x8 bH1 = *(const bf16x8*)(khg + kb + 32);
    bf16x8 bM0 = *(const bf16x8*)(kmg + kb);
    bf16x8 bM1 = *(const bf16x8*)(kmg + kb + 32);
    bf16x8 bL0 = *(const bf16x8*)(klg + kb);
    bf16x8 bL1 = *(const bf16x8*)(klg + kb + 32);
    f32x4 accA = {}, accB = {}, accC = {};
    __builtin_amdgcn_s_setprio(1);               // T5: favor MFMA-issuing wave
    accA = mfma16(aH[0], bH0, accA);             // hh, k-half 0
    accB = mfma16(aH[1], bH1, accB);             // hh, k-half 1
    accC = mfma16(aH[0], bM0, accC);             // hm
    accC = mfma16(aH[1], bM1, accC);
    accC = mfma16(aM[0], bH0, accC);             // mh
    accC = mfma16(aM[1], bH1, accC);
    accC = mfma16(aH[0], bL0, accC);             // hl
    accC = mfma16(aH[1], bL1, accC);
    accC = mfma16(aL[0], bH0, accC);             // lh
    accC = mfma16(aL[1], bH1, accC);
    accC = mfma16(aM[0], bM0, accC);             // mm
    accC = mfma16(aM[1], bM1, accC);
    __builtin_amdgcn_s_setprio(0);
    int key = wv * 128 + t2 * 16 + l16;
#pragma unroll
    for (int r = 0; r < 4; r++)
      sc[(quad * 4 + r) * 1028 + key] = ((accA[r] + accB[r]) + accC[r]) * 0.125f;
  }
  __syncthreads();                        // the ONLY block barrier

  // ---- wave wv owns queries 2wv, 2wv+1 (sc rows 2wv, 2wv+1) ----
  float fv[2][16];
#pragma unroll
  for (int i = 0; i < 16; i++) {
    fv[0][i] = sc[(2 * wv)     * 1028 + i * 64 + lane];
    fv[1][i] = sc[(2 * wv + 1) * 1028 + i * 64 + lane];
  }
  wave_fence();                           // row reads done before overlay

  // wave-owned scratch INSIDE the wave's own rows (no other wave touches them)
  uint32_t* bins  = (uint32_t*)(sc + (2 * wv) * 1028);   // 512 u32 (<=1028 fl)
  float*    candV = (float*)bins;                        // reuse after scan
  ushort*   candI = (ushort*)(bins + 64);
  float*    selWw = sc + (2 * wv + 1) * 1028;            // 128 floats
  ushort*   selIw = (ushort*)(selWw + 128);              // 128 u16

  const uint64_t lt = (1ull << lane) - 1ull;
  for (int qi = 0; qi < 2; qi++) {
    const float* fq = fv[qi];
    // zero bins (512 u32 per wave)
    *(uint4*)(bins + lane * 8)     = uint4{0, 0, 0, 0};
    *(uint4*)(bins + lane * 8 + 4) = uint4{0, 0, 0, 0};
    wave_fence();
    // histogram: bin = clamp((int)(f*32+256), 0, 511) — monotone in f
#pragma unroll
    for (int i = 0; i < 16; i++) {
      int b = (int)fmaxf(0.f, fminf(511.f, fmaf(fq[i], 32.f, 256.f)));
      atomicAdd(bins + b, 1u);
    }
    wave_fence();
    // descending scan: lane covers bins [504-8*lane, 511-8*lane]
    int base = 504 - 8 * lane;
    uint4 h0 = *(const uint4*)(bins + base);
    uint4 h1 = *(const uint4*)(bins + base + 4);
    uint32_t s_l = h0.x + h0.y + h0.z + h0.w + h1.x + h1.y + h1.z + h1.w;
    uint32_t x = s_l;
#pragma unroll
    for (int off = 1; off < 64; off <<= 1) {
      uint32_t y = __shfl_up(x, off);
      if (lane >= off) x += y;
    }
    uint32_t P = x - s_l;               // count in bins strictly above lane's range
    uint32_t harr[8] = { h1.w, h1.z, h1.y, h1.x, h0.w, h0.z, h0.y, h0.x };
    uint32_t cb = P, G = 0;
    int foundc = -1;
#pragma unroll
    for (int c = 0; c < 8; c++) {
      uint32_t hc = harr[c];
      if (foundc < 0 && (int)cb < 64 && (int)(cb + hc) >= 64) { foundc = c; G = cb; }
      cb += hc;
    }
    uint64_t fm = __ballot(foundc >= 0);
    int src   = __ffsll((unsigned long long)fm) - 1;
    int Bstar = __shfl((foundc >= 0) ? (511 - 8 * lane - foundc) : 0, src);
    int Gs    = __shfl((int)G, src);
    int needed = 64 - Gs;
    wave_fence();                        // scan reads done before overlay writes

    // prefill candidate slots so the rank loop below is compile-time 64-iter
    candV[lane] = -3.402823466e+38f;     // -FLT_MAX: never out-ranks a real score
    candI[lane] = (ushort)0xffff;
    wave_fence();                        // prefill visible before pass-1 writes

    // pass 1: bin > Bstar -> selected (Gs total), slots [0, Gs)
    int pos = 0, cT = 0;
#pragma unroll
    for (int i = 0; i < 16; i++) {
      int b = (int)fmaxf(0.f, fminf(511.f, fmaf(fq[i], 32.f, 256.f)));
      bool hi = b > Bstar;
      bool cd = (b == Bstar);
      uint64_t hm = __ballot(hi);
      uint64_t em = __ballot(cd);
      int p  = pos + (int)__popcll(hm & lt);
      int cp = cT  + (int)__popcll(em & lt);
      if (hi) { selWw[qi * 64 + p] = fq[i]; selIw[qi * 64 + p] = (ushort)(i * 64 + lane); }
      if (cd && cp < 64) { candV[cp] = fq[i]; candI[cp] = (ushort)(i * 64 + lane); }
      pos += (int)__popcll(hm);
      cT  += (int)__popcll(em);
    }
    wave_fence();
    // exact ranking inside boundary bin (value desc, index asc) — fixed 64
    // iterations, fully unrolled: 128 pipelined LDS broadcast reads. Slots
    // >= cT hold -FLT_MAX and never increment rank of a real candidate.
    int C = cT < 64 ? cT : 64;
    float mv = candV[lane];
    int   mi = candI[lane];
    int rank = 0;
#pragma unroll
    for (int i = 0; i < 64; i++) {
      float ov = candV[i]; int oi = candI[i];
      rank += (ov > mv || (ov == mv && oi < mi)) ? 1 : 0;
    }
    bool take = (lane < C) && (rank < needed);
    uint64_t tm = __ballot(take);
    int slot = Gs + (int)__popcll(tm & lt);
    if (take) { selWw[qi * 64 + slot] = mv; selIw[qi * 64 + slot] = (ushort)mi; }
    wave_fence();
    // softmax over the 64 selected scores
    float sv = selWw[qi * 64 + lane];
    float mx = sv;
#pragma unroll
    for (int off = 32; off >= 1; off >>= 1) mx = fmaxf(mx, __shfl_xor(mx, off));
    float e = __expf(sv - mx);
    float sum = e;
#pragma unroll
    for (int off = 32; off >= 1; off >>= 1) sum += __shfl_xor(sum, off);
    selWw[qi * 64 + lane] = e / sum;
    wave_fence();
  }
  // NO block barrier: PV consumes this wave's own selW/selI only.

  // ---- PV (wave-local): lane -> ql = lane>>5, jh = (lane>>4)&1,
  //      d-block = (lane&15)*4. 32-deep batched gather prefetch.
  {
    int ql = lane >> 5, jh = (lane >> 4) & 1, dblk = (lane & 15) * 4;
    const float* vb = vg + (size_t)bh * SS * HD;
    f32x4 a4 = {};
    float wreg[32]; int ireg[32];
#pragma unroll
    for (int j = 0; j < 32; j++) {
      int jj = jh * 32 + j;
      wreg[j] = selWw[ql * 64 + jj];
      ireg[j] = selIw[ql * 64 + jj];
    }
#pragma unroll
    for (int j = 0; j < 32; j++) {
      f32x4 v4 = *(const f32x4*)(vb + (size_t)ireg[j] * HD + dblk);
      a4 += wreg[j] * v4;
    }
#pragma unroll
    for (int c = 0; c < 4; c++) a4[c] += __shfl_xor(a4[c], 16);
    if (jh == 0) {
      int qg = q0 + 2 * wv + ql;
      size_t dofs = ((size_t)b_ * SS + qg) * EE + h_ * HD + dblk;
      bf16x4 oh, om;
#pragma unroll
      for (int j = 0; j < 4; j++) {
        bf16_t hh = (bf16_t)a4[j];
        oh[j] = hh;
        om[j] = (bf16_t)(a4[j] - (float)hh);
      }
      *(bf16x4*)(attnH + dofs) = oh;
      *(bf16x4*)(attnM + dofs) = om;
    }
  }
}

// ---------------------------------------------------------------------------
extern "C" void kernel_launch(void* const* d_in, const int* in_sizes, int n_in,
                              void* d_out, int out_size, void* d_ws, size_t ws_size,
                              hipStream_t stream)
{
  const float* x  = (const float*)d_in[0];
  const float* Wq = (const float*)d_in[1];
  const float* bq = (const float*)d_in[2];
  const float* Wk = (const float*)d_in[3];
  const float* bk = (const float*)d_in[4];
  const float* Wv = (const float*)d_in[5];
  const float* bv = (const float*)d_in[6];
  const float* Wo = (const float*)d_in[7];
  const float* bo = (const float*)d_in[8];

  bf16_t* base = (bf16_t*)d_ws;
  bf16_t *xh = base,            *xm = xh + NX_,  *xl = xm + NX_;
  bf16_t *wqh = base + 3*NX_,           *wqm = wqh + NW_, *wql = wqm + NW_;
  bf16_t *wkh = base + 3*NX_ + 3*NW_,   *wkm = wkh + NW_, *wkl = wkm + NW_;
  bf16_t *wvh = base + 3*NX_ + 6*NW_,   *wvm = wvh + NW_;
  bf16_t *woh = base + 3*NX_ + 9*NW_,   *wom = woh + NW_;
  bf16_t *p2 = base + 3*NX_ + 12*NW_;
  bf16_t *qh = p2,          *qm = qh + NX_, *ql = qm + NX_;
  bf16_t *kh = ql + NX_,    *km = kh + NX_, *kl = km + NX_;
  float  *vws = (float*)(kl + NX_);
  bf16_t *ath = (bf16_t*)(vws + NX_), *atm = ath + NX_;

  dim3 blk(256);
  presplit_all<<<dim3(6144), blk, 0, stream>>>(x, Wq, Wk, Wv, Wo, base);

  // fused Q+K: 128x64 tile, grid (16, 16, 2) = 512 blocks (2/CU)
  gemm_qk<<<dim3(EE / 64, (NB * SS) / 128, 2), blk, 0, stream>>>(
      xh, xm, xl, wqh, wqm, wql, wkh, wkm, wkl, bq, bk,
      qh, qm, ql, kh, km, kl);

  // V: 64x64 tile, grid (16, 32) = 512 blocks (2/CU)
  gemm_nl2<1><<<dim3(EE / 64, (NB * SS) / 64), blk, 0, stream>>>(
      xh, xm, wvh, wvm, bv, vws);

  attn_topk<<<dim3(NBH * (SS / 16)), dim3(512), 0, stream>>>(
      qh, qm, ql, kh, km, kl, vws, ath, atm);

  // O: 64x64 tile, grid (16, 32) = 512 blocks (2/CU)
  gemm_nl2<2><<<dim3(EE / 64, (NB * SS) / 64), blk, 0, stream>>>(
      ath, atm, woh, wom, bo, (float*)d_out);
}

// Round 12
// 343.311 us; speedup vs baseline: 1.1607x; 1.1607x over previous
//
#include <hip/hip_runtime.h>
#include <hip/hip_bf16.h>
#include <stdint.h>

// DynamicSparseAttention MI355X r20 — fp32 I/O.
// History: r9 @322 (attn 148). r10/r16 spill fails. r11-r13 block-config
// fails (occupancy pinned ~14 waves/CU). r14 @317.3 (wave-independent tail).
// r17 @313.9 (+setprio T5, attn 137.3). r18 @313.8 BEST (XCD swizzle + PV-32,
// neutral-kept). r19 FAILED: fixed-64 FULL unroll rank loop -> compiler
// hoisted all 128 LDS reads -> scratch spill (WRITE 139MB, attn 225).
// r20: same rank-loop theory, register-bounded: fixed-64 with #pragma
// unroll 4 (<=8 reads in flight, ~16 live values, no spill) + -FLT_MAX
// prefill (selection bit-identical: junk slots never out-rank real
// candidates; take still requires lane<C). Everything else r18-exact.

typedef __bf16 bf16_t;
typedef bf16_t bf16x8 __attribute__((ext_vector_type(8)));
typedef bf16_t bf16x4 __attribute__((ext_vector_type(4)));
typedef float  f32x4  __attribute__((ext_vector_type(4)));

#define NB 2
#define SS 1024
#define EE 1024
#define NH 16
#define HD 64
#define NBH (NB*NH)
#define NX_ ((size_t)NB*SS*EE)   // 2,097,152
#define NW_ ((size_t)EE*EE)      // 1,048,576

__device__ __forceinline__ f32x4 mfma16(bf16x8 a, bf16x8 b, f32x4 c) {
  return __builtin_amdgcn_mfma_f32_16x16x32_bf16(a, b, c, 0, 0, 0);
}

__device__ __forceinline__ void split3(float x, bf16_t& h, bf16_t& m, bf16_t& l) {
  h = (bf16_t)x;
  float r = x - (float)h;     // exact
  m = (bf16_t)r;
  float r2 = r - (float)m;    // exact
  l = (bf16_t)r2;             // residual <= 2^-27 |x|
}

// wave-local LDS ordering fence (per-wave scratch; no cross-wave deps)
__device__ __forceinline__ void wave_fence() {
  __builtin_amdgcn_wave_barrier();
  __builtin_amdgcn_s_waitcnt(0);
  __builtin_amdgcn_wave_barrier();
}

// async global->LDS, 16B per lane; LDS dest = wave-uniform base + lane*16
__device__ __forceinline__ void gld16(const bf16_t* g, bf16_t* l) {
  __builtin_amdgcn_global_load_lds(
      (const __attribute__((address_space(1))) void*)g,
      (__attribute__((address_space(3))) void*)l, 16, 0, 0);
}

// ---------------------------------------------------------------------------
// fused presplit of x, Wq, Wk, Wv, Wo into h/m/l limb arrays (unchanged)
// ---------------------------------------------------------------------------
__global__ __launch_bounds__(256) void presplit_all(
    const float* __restrict__ x,  const float* __restrict__ wq,
    const float* __restrict__ wk, const float* __restrict__ wv,
    const float* __restrict__ wo, bf16_t* __restrict__ base)
{
  const int blk = blockIdx.x;
  const float* src; bf16_t* h; size_t n; int i;
  if (blk < 2048)      { src = x;  h = base;                   n = NX_; i = blk;        }
  else if (blk < 3072) { src = wq; h = base + 3*NX_;           n = NW_; i = blk - 2048; }
  else if (blk < 4096) { src = wk; h = base + 3*NX_ + 3*NW_;   n = NW_; i = blk - 3072; }
  else if (blk < 5120) { src = wv; h = base + 3*NX_ + 6*NW_;   n = NW_; i = blk - 4096; }
  else                 { src = wo; h = base + 3*NX_ + 9*NW_;   n = NW_; i = blk - 5120; }
  bf16_t* m = h + n;
  bf16_t* l = m + n;
  int idx = i * 256 + threadIdx.x;            // float4 index
  float4 v = ((const float4*)src)[idx];
  float t[4] = { v.x, v.y, v.z, v.w };
  bf16x4 hv, mv, lv;
#pragma unroll
  for (int j = 0; j < 4; j++) {
    bf16_t a, b, c;
    split3(t[j], a, b, c);
    hv[j] = a; mv[j] = b; lv[j] = c;
  }
  ((bf16x4*)h)[idx] = hv;
  ((bf16x4*)m)[idx] = mv;
  ((bf16x4*)l)[idx] = lv;
}

// ---------------------------------------------------------------------------
// Fused Q+K projection GEMM, 128x64 tile. grid (16, 16, 2) = 512 blocks.
// XCD-contiguous swizzle (r18, neutral but harmless). Math unchanged.
// ---------------------------------------------------------------------------
__global__ __launch_bounds__(256, 2) void gemm_qk(
    const bf16_t* __restrict__ Ah, const bf16_t* __restrict__ Am,
    const bf16_t* __restrict__ Al,
    const bf16_t* __restrict__ Bqh, const bf16_t* __restrict__ Bqm,
    const bf16_t* __restrict__ Bql,
    const bf16_t* __restrict__ Bkh, const bf16_t* __restrict__ Bkm,
    const bf16_t* __restrict__ Bkl,
    const float* __restrict__ biasq, const float* __restrict__ biask,
    bf16_t* __restrict__ qH, bf16_t* __restrict__ qM, bf16_t* __restrict__ qL,
    bf16_t* __restrict__ kH, bf16_t* __restrict__ kM, bf16_t* __restrict__ kL)
{
  __shared__ bf16_t As[3][128 * 32];   // row-major, unpadded (gld16 lane order)
  __shared__ bf16_t Bs[3][64 * 32];

  // XCD-contiguous remap (bijective on [0,512); 512%8==0)
  const int flat = blockIdx.x + 16 * blockIdx.y + 256 * blockIdx.z;
  const int eff  = (flat & 7) * 64 + (flat >> 3);
  const int bx = eff & 15, by = (eff >> 4) & 15, z = eff >> 8;

  const bf16_t* AP[3] = { Ah, Am, Al };
  const bf16_t* BP[3] = { z ? Bkh : Bqh, z ? Bkm : Bqm, z ? Bkl : Bql };
  const float* bias = z ? biask : biasq;
  bf16_t* dH = z ? kH : qH;
  bf16_t* dM = z ? kM : qM;
  bf16_t* dL = z ? kL : qL;

  const int tid  = threadIdx.x;
  const int wv   = tid >> 6, lane = tid & 63;
  const int quad = lane >> 4, l16 = lane & 15;
  const int m0 = by * 128, n0 = bx * 64;
  const int wm = (wv & 1) * 64, wn = (wv >> 1) * 32;

  // staging: A rows [wv*32, wv*32+32) via two gld16; B rows [wv*16, wv*16+16)
  const int arow = wv * 32 + (lane >> 2);
  const int brow = wv * 16 + (lane >> 2);
  const int q8   = (lane & 3) * 8;
  const size_t aoff0 = (size_t)(m0 + arow) * 1024 + q8;
  const size_t boff  = (size_t)(n0 + brow) * 1024 + q8;

  f32x4 accH0[4][2] = {};   // hh, k < 512
  f32x4 accH1[4][2] = {};   // hh, k >= 512
  f32x4 accC [4][2] = {};   // corrections (small magnitude)

  for (int k0 = 0; k0 < 1024; k0 += 32) {
    __syncthreads();                     // previous iter's frags consumed
#pragma unroll
    for (int L = 0; L < 3; L++) {
      gld16(AP[L] + aoff0 + k0,              &As[L][(wv * 32) * 32]);
      gld16(AP[L] + aoff0 + 16 * 1024 + k0,  &As[L][(wv * 32 + 16) * 32]);
      gld16(BP[L] + boff + k0,               &Bs[L][(wv * 16) * 32]);
    }
    __syncthreads();                     // staging visible

    bf16x8 bfr[2][3];
#pragma unroll
    for (int nt = 0; nt < 2; nt++)
#pragma unroll
      for (int L = 0; L < 3; L++)
        bfr[nt][L] = *(const bf16x8*)&Bs[L][(wn + nt * 16 + l16) * 32 + quad * 8];

    const bool hi = (k0 >= 512);
#pragma unroll
    for (int mt = 0; mt < 4; mt++) {
      bf16x8 af[3];
#pragma unroll
      for (int L = 0; L < 3; L++)
        af[L] = *(const bf16x8*)&As[L][(wm + mt * 16 + l16) * 32 + quad * 8];
#pragma unroll
      for (int nt = 0; nt < 2; nt++) {
        f32x4& H = hi ? accH1[mt][nt] : accH0[mt][nt];
        H = mfma16(af[0], bfr[nt][0], H);                      // hh
        f32x4 c = accC[mt][nt];
        c = mfma16(af[0], bfr[nt][1], c);                      // hm
        c = mfma16(af[1], bfr[nt][0], c);                      // mh
        c = mfma16(af[0], bfr[nt][2], c);                      // hl
        c = mfma16(af[2], bfr[nt][0], c);                      // lh
        c = mfma16(af[1], bfr[nt][1], c);                      // mm
        accC[mt][nt] = c;
      }
    }
  }

  // epilogue: D[row=quad*4+r][col=l16] -> 3-way split limbs at [B,H,S,HD]
#pragma unroll
  for (int mt = 0; mt < 4; mt++)
#pragma unroll
  for (int nt = 0; nt < 2; nt++)
#pragma unroll
  for (int r  = 0; r  < 4;  r++) {
    int gm = m0 + wm + mt * 16 + quad * 4 + r;
    int gn = n0 + wn + nt * 16 + l16;
    float v = (accH0[mt][nt][r] + accH1[mt][nt][r]) + accC[mt][nt][r] + bias[gn];
    int b_ = gm >> 10, s_ = gm & 1023, h_ = gn >> 6, d_ = gn & 63;
    size_t di = (((size_t)b_ * NH + h_) * SS + s_) * HD + d_;
    bf16_t hh, mm, ll;
    split3(v, hh, mm, ll);
    dH[di] = hh; dM[di] = mm; dL[di] = ll;
  }
}

// ---------------------------------------------------------------------------
// 3-product NT GEMM (hh k-split + hm/mh corrections), 64x64 tile, grid (16,32).
// MODE 1: fp32 [B,H,S,HD] (v-proj).  MODE 2: fp32 row-major [M,N] (o-proj).
// XCD-contiguous swizzle (r18). Math unchanged.
// ---------------------------------------------------------------------------
template<int MODE>
__global__ __launch_bounds__(256, 4) void gemm_nl2(
    const bf16_t* __restrict__ Ah, const bf16_t* __restrict__ Am,
    const bf16_t* __restrict__ Bh, const bf16_t* __restrict__ Bm,
    const float* __restrict__ bias, float* __restrict__ dF)
{
  __shared__ bf16_t As[2][64 * 32];
  __shared__ bf16_t Bs[2][64 * 32];

  const bf16_t* AP[2] = { Ah, Am };
  const bf16_t* BP[2] = { Bh, Bm };

  // XCD-contiguous remap (bijective on [0,512))
  const int flat = blockIdx.x + 16 * blockIdx.y;
  const int eff  = (flat & 7) * 64 + (flat >> 3);
  const int bx = eff & 15, by = eff >> 4;

  const int tid  = threadIdx.x;
  const int wv   = tid >> 6, lane = tid & 63;
  const int quad = lane >> 4, l16 = lane & 15;
  const int m0 = by * 64, n0 = bx * 64;
  const int wm = (wv & 1) * 32, wn = (wv >> 1) * 32;

  const int srow = wv * 16 + (lane >> 2);
  const int q8   = (lane & 3) * 8;
  const size_t aoff = (size_t)(m0 + srow) * 1024 + q8;
  const size_t boff = (size_t)(n0 + srow) * 1024 + q8;

  f32x4 accH0[2][2] = {};
  f32x4 accH1[2][2] = {};
  f32x4 accC [2][2] = {};

  for (int k0 = 0; k0 < 1024; k0 += 32) {
    __syncthreads();
#pragma unroll
    for (int L = 0; L < 2; L++) {
      gld16(AP[L] + aoff + k0, &As[L][(wv * 16) * 32]);
      gld16(BP[L] + boff + k0, &Bs[L][(wv * 16) * 32]);
    }
    __syncthreads();

    bf16x8 bfr[2][2];
#pragma unroll
    for (int nt = 0; nt < 2; nt++)
#pragma unroll
      for (int L = 0; L < 2; L++)
        bfr[nt][L] = *(const bf16x8*)&Bs[L][(wn + nt * 16 + l16) * 32 + quad * 8];

    const bool hi = (k0 >= 512);
#pragma unroll
    for (int mt = 0; mt < 2; mt++) {
      bf16x8 af[2];
#pragma unroll
      for (int L = 0; L < 2; L++)
        af[L] = *(const bf16x8*)&As[L][(wm + mt * 16 + l16) * 32 + quad * 8];
#pragma unroll
      for (int nt = 0; nt < 2; nt++) {
        f32x4& H = hi ? accH1[mt][nt] : accH0[mt][nt];
        H = mfma16(af[0], bfr[nt][0], H);                      // hh
        f32x4 c = accC[mt][nt];
        c = mfma16(af[0], bfr[nt][1], c);                      // hm
        c = mfma16(af[1], bfr[nt][0], c);                      // mh
        accC[mt][nt] = c;
      }
    }
  }

#pragma unroll
  for (int mt = 0; mt < 2; mt++)
#pragma unroll
  for (int nt = 0; nt < 2; nt++)
#pragma unroll
  for (int r  = 0; r  < 4;  r++) {
    int gm = m0 + wm + mt * 16 + quad * 4 + r;
    int gn = n0 + wn + nt * 16 + l16;
    float v = (accH0[mt][nt][r] + accH1[mt][nt][r]) + accC[mt][nt][r] + bias[gn];
    if (MODE == 2) {
      dF[(size_t)gm * 1024 + gn] = v;
    } else {
      int b_ = gm >> 10, s_ = gm & 1023, h_ = gn >> 6, d_ = gn & 63;
      dF[(((size_t)b_ * NH + h_) * SS + s_) * HD + d_] = v;
    }
  }
}

// ---------------------------------------------------------------------------
// Fused attention r20 (= r18 + bounded fixed-64 rank loop): one (b,h) x 16
// queries, 512 thr / 8 waves. Score phase: single-chunk 16x1028 transpose,
// wave wv covers keys [wv*128,+128), r9-exact accumulation, s_setprio(1)
// around each t2's 12-MFMA cluster. ONE block barrier. Tail wave-independent:
// wave wv owns queries 2wv, 2wv+1; bins in sc row 2wv, selW/selI in row
// 2wv+1. Rank: candV prefilled -FLT_MAX -> fixed-64 loop with #pragma
// unroll 4 (4-deep pipelined reads, bounded registers — r19's full unroll
// spilled). PV wave-local, 32-deep batched gather.
// ---------------------------------------------------------------------------
__global__ __launch_bounds__(512, 4) void attn_topk(
    const bf16_t* __restrict__ qhg, const bf16_t* __restrict__ qmg,
    const bf16_t* __restrict__ qlg,
    const bf16_t* __restrict__ khg, const bf16_t* __restrict__ kmg,
    const bf16_t* __restrict__ klg,
    const float*  __restrict__ vg,
    bf16_t* __restrict__ attnH, bf16_t* __restrict__ attnM)
{
  __shared__ float sc[16 * 1028];       // scores; rows become per-wave scratch

  const int tid  = threadIdx.x;
  const int wv   = tid >> 6, lane = tid & 63;
  const int quad = lane >> 4, l16 = lane & 15;
  const int xcd = blockIdx.x & 7;
  const int g   = blockIdx.x >> 3;        // 0..255
  const int bh  = xcd + 8 * (g >> 6);     // 0..31 (bh pinned to XCD)
  const int qt  = g & 63;
  const int b_ = bh >> 4, h_ = bh & 15;
  const int q0 = qt * 16;

  // A-frags direct from global: lane holds q[m=l16][k=quad*8+j]
  const size_t qbase = ((size_t)bh * SS + q0 + l16) * HD + quad * 8;
  bf16x8 aH[2], aM[2], aL[2];
#pragma unroll
  for (int ks = 0; ks < 2; ks++) {
    aH[ks] = *(const bf16x8*)(qhg + qbase + ks * 32);
    aM[ks] = *(const bf16x8*)(qmg + qbase + ks * 32);
    aL[ks] = *(const bf16x8*)(qlg + qbase + ks * 32);
  }

  // ---- score phase: wave wv covers keys [wv*128, wv*128+128) — r9-exact ----
  const size_t kwb = ((size_t)bh * SS + wv * 128 + l16) * HD + quad * 8;
#pragma unroll 4
  for (int t2 = 0; t2 < 8; t2++) {
    const size_t kb = kwb + (size_t)t2 * 16 * HD;
    bf16x8 bH0 = *(const bf16x8*)(khg + kb);
    bf16x8 bH1 = *(const bf16x8*)(khg + kb + 32);
    bf16x8 bM0 = *(const bf16x8*)(kmg + kb);
    bf16x8 bM1 = *(const bf16x8*)(kmg + kb + 32);
    bf16x8 bL0 = *(const bf16x8*)(klg + kb);
    bf16x8 bL1 = *(const bf16x8*)(klg + kb + 32);
    f32x4 accA = {}, accB = {}, accC = {};
    __builtin_amdgcn_s_setprio(1);               // T5: favor MFMA-issuing wave
    accA = mfma16(aH[0], bH0, accA);             // hh, k-half 0
    accB = mfma16(aH[1], bH1, accB);             // hh, k-half 1
    accC = mfma16(aH[0], bM0, accC);             // hm
    accC = mfma16(aH[1], bM1, accC);
    accC = mfma16(aM[0], bH0, accC);             // mh
    accC = mfma16(aM[1], bH1, accC);
    accC = mfma16(aH[0], bL0, accC);             // hl
    accC = mfma16(aH[1], bL1, accC);
    accC = mfma16(aL[0], bH0, accC);             // lh
    accC = mfma16(aL[1], bH1, accC);
    accC = mfma16(aM[0], bM0, accC);             // mm
    accC = mfma16(aM[1], bM1, accC);
    __builtin_amdgcn_s_setprio(0);
    int key = wv * 128 + t2 * 16 + l16;
#pragma unroll
    for (int r = 0; r < 4; r++)
      sc[(quad * 4 + r) * 1028 + key] = ((accA[r] + accB[r]) + accC[r]) * 0.125f;
  }
  __syncthreads();                        // the ONLY block barrier

  // ---- wave wv owns queries 2wv, 2wv+1 (sc rows 2wv, 2wv+1) ----
  float fv[2][16];
#pragma unroll
  for (int i = 0; i < 16; i++) {
    fv[0][i] = sc[(2 * wv)     * 1028 + i * 64 + lane];
    fv[1][i] = sc[(2 * wv + 1) * 1028 + i * 64 + lane];
  }
  wave_fence();                           // row reads done before overlay

  // wave-owned scratch INSIDE the wave's own rows (no other wave touches them)
  uint32_t* bins  = (uint32_t*)(sc + (2 * wv) * 1028);   // 512 u32 (<=1028 fl)
  float*    candV = (float*)bins;                        // reuse after scan
  ushort*   candI = (ushort*)(bins + 64);
  float*    selWw = sc + (2 * wv + 1) * 1028;            // 128 floats
  ushort*   selIw = (ushort*)(selWw + 128);              // 128 u16

  const uint64_t lt = (1ull << lane) - 1ull;
  for (int qi = 0; qi < 2; qi++) {
    const float* fq = fv[qi];
    // zero bins (512 u32 per wave)
    *(uint4*)(bins + lane * 8)     = uint4{0, 0, 0, 0};
    *(uint4*)(bins + lane * 8 + 4) = uint4{0, 0, 0, 0};
    wave_fence();
    // histogram: bin = clamp((int)(f*32+256), 0, 511) — monotone in f
#pragma unroll
    for (int i = 0; i < 16; i++) {
      int b = (int)fmaxf(0.f, fminf(511.f, fmaf(fq[i], 32.f, 256.f)));
      atomicAdd(bins + b, 1u);
    }
    wave_fence();
    // descending scan: lane covers bins [504-8*lane, 511-8*lane]
    int base = 504 - 8 * lane;
    uint4 h0 = *(const uint4*)(bins + base);
    uint4 h1 = *(const uint4*)(bins + base + 4);
    uint32_t s_l = h0.x + h0.y + h0.z + h0.w + h1.x + h1.y + h1.z + h1.w;
    uint32_t x = s_l;
#pragma unroll
    for (int off = 1; off < 64; off <<= 1) {
      uint32_t y = __shfl_up(x, off);
      if (lane >= off) x += y;
    }
    uint32_t P = x - s_l;               // count in bins strictly above lane's range
    uint32_t harr[8] = { h1.w, h1.z, h1.y, h1.x, h0.w, h0.z, h0.y, h0.x };
    uint32_t cb = P, G = 0;
    int foundc = -1;
#pragma unroll
    for (int c = 0; c < 8; c++) {
      uint32_t hc = harr[c];
      if (foundc < 0 && (int)cb < 64 && (int)(cb + hc) >= 64) { foundc = c; G = cb; }
      cb += hc;
    }
    uint64_t fm = __ballot(foundc >= 0);
    int src   = __ffsll((unsigned long long)fm) - 1;
    int Bstar = __shfl((foundc >= 0) ? (511 - 8 * lane - foundc) : 0, src);
    int Gs    = __shfl((int)G, src);
    int needed = 64 - Gs;
    wave_fence();                        // scan reads done before overlay writes

    // prefill candidate slots so the rank loop below is compile-time 64-iter
    candV[lane] = -3.402823466e+38f;     // -FLT_MAX: never out-ranks a real score
    candI[lane] = (ushort)0xffff;
    wave_fence();                        // prefill visible before pass-1 writes

    // pass 1: bin > Bstar -> selected (Gs total), slots [0, Gs)
    int pos = 0, cT = 0;
#pragma unroll
    for (int i = 0; i < 16; i++) {
      int b = (int)fmaxf(0.f, fminf(511.f, fmaf(fq[i], 32.f, 256.f)));
      bool hi = b > Bstar;
      bool cd = (b == Bstar);
      uint64_t hm = __ballot(hi);
      uint64_t em = __ballot(cd);
      int p  = pos + (int)__popcll(hm & lt);
      int cp = cT  + (int)__popcll(em & lt);
      if (hi) { selWw[qi * 64 + p] = fq[i]; selIw[qi * 64 + p] = (ushort)(i * 64 + lane); }
      if (cd && cp < 64) { candV[cp] = fq[i]; candI[cp] = (ushort)(i * 64 + lane); }
      pos += (int)__popcll(hm);
      cT  += (int)__popcll(em);
    }
    wave_fence();
    // exact ranking inside boundary bin (value desc, index asc) — fixed 64
    // iterations, partial unroll 4: 4-deep pipelined broadcast reads with
    // bounded register pressure (r19's full unroll spilled). Slots >= cT
    // hold -FLT_MAX and never increment a real candidate's rank.
    int C = cT < 64 ? cT : 64;
    float mv = candV[lane];
    int   mi = candI[lane];
    int rank = 0;
#pragma unroll 4
    for (int i = 0; i < 64; i++) {
      float ov = candV[i]; int oi = candI[i];
      rank += (ov > mv || (ov == mv && oi < mi)) ? 1 : 0;
    }
    bool take = (lane < C) && (rank < needed);
    uint64_t tm = __ballot(take);
    int slot = Gs + (int)__popcll(tm & lt);
    if (take) { selWw[qi * 64 + slot] = mv; selIw[qi * 64 + slot] = (ushort)mi; }
    wave_fence();
    // softmax over the 64 selected scores
    float sv = selWw[qi * 64 + lane];
    float mx = sv;
#pragma unroll
    for (int off = 32; off >= 1; off >>= 1) mx = fmaxf(mx, __shfl_xor(mx, off));
    float e = __expf(sv - mx);
    float sum = e;
#pragma unroll
    for (int off = 32; off >= 1; off >>= 1) sum += __shfl_xor(sum, off);
    selWw[qi * 64 + lane] = e / sum;
    wave_fence();
  }
  // NO block barrier: PV consumes this wave's own selW/selI only.

  // ---- PV (wave-local): lane -> ql = lane>>5, jh = (lane>>4)&1,
  //      d-block = (lane&15)*4. 32-deep batched gather prefetch.
  {
    int ql = lane >> 5, jh = (lane >> 4) & 1, dblk = (lane & 15) * 4;
    const float* vb = vg + (size_t)bh * SS * HD;
    f32x4 a4 = {};
    float wreg[32]; int ireg[32];
#pragma unroll
    for (int j = 0; j < 32; j++) {
      int jj = jh * 32 + j;
      wreg[j] = selWw[ql * 64 + jj];
      ireg[j] = selIw[ql * 64 + jj];
    }
#pragma unroll
    for (int j = 0; j < 32; j++) {
      f32x4 v4 = *(const f32x4*)(vb + (size_t)ireg[j] * HD + dblk);
      a4 += wreg[j] * v4;
    }
#pragma unroll
    for (int c = 0; c < 4; c++) a4[c] += __shfl_xor(a4[c], 16);
    if (jh == 0) {
      int qg = q0 + 2 * wv + ql;
      size_t dofs = ((size_t)b_ * SS + qg) * EE + h_ * HD + dblk;
      bf16x4 oh, om;
#pragma unroll
      for (int j = 0; j < 4; j++) {
        bf16_t hh = (bf16_t)a4[j];
        oh[j] = hh;
        om[j] = (bf16_t)(a4[j] - (float)hh);
      }
      *(bf16x4*)(attnH + dofs) = oh;
      *(bf16x4*)(attnM + dofs) = om;
    }
  }
}

// ---------------------------------------------------------------------------
extern "C" void kernel_launch(void* const* d_in, const int* in_sizes, int n_in,
                              void* d_out, int out_size, void* d_ws, size_t ws_size,
                              hipStream_t stream)
{
  const float* x  = (const float*)d_in[0];
  const float* Wq = (const float*)d_in[1];
  const float* bq = (const float*)d_in[2];
  const float* Wk = (const float*)d_in[3];
  const float* bk = (const float*)d_in[4];
  const float* Wv = (const float*)d_in[5];
  const float* bv = (const float*)d_in[6];
  const float* Wo = (const float*)d_in[7];
  const float* bo = (const float*)d_in[8];

  bf16_t* base = (bf16_t*)d_ws;
  bf16_t *xh = base,            *xm = xh + NX_,  *xl = xm + NX_;
  bf16_t *wqh = base + 3*NX_,           *wqm = wqh + NW_, *wql = wqm + NW_;
  bf16_t *wkh = base + 3*NX_ + 3*NW_,   *wkm = wkh + NW_, *wkl = wkm + NW_;
  bf16_t *wvh = base + 3*NX_ + 6*NW_,   *wvm = wvh + NW_;
  bf16_t *woh = base + 3*NX_ + 9*NW_,   *wom = woh + NW_;
  bf16_t *p2 = base + 3*NX_ + 12*NW_;
  bf16_t *qh = p2,          *qm = qh + NX_, *ql = qm + NX_;
  bf16_t *kh = ql + NX_,    *km = kh + NX_, *kl = km + NX_;
  float  *vws = (float*)(kl + NX_);
  bf16_t *ath = (bf16_t*)(vws + NX_), *atm = ath + NX_;

  dim3 blk(256);
  presplit_all<<<dim3(6144), blk, 0, stream>>>(x, Wq, Wk, Wv, Wo, base);

  // fused Q+K: 128x64 tile, grid (16, 16, 2) = 512 blocks (2/CU)
  gemm_qk<<<dim3(EE / 64, (NB * SS) / 128, 2), blk, 0, stream>>>(
      xh, xm, xl, wqh, wqm, wql, wkh, wkm, wkl, bq, bk,
      qh, qm, ql, kh, km, kl);

  // V: 64x64 tile, grid (16, 32) = 512 blocks (2/CU)
  gemm_nl2<1><<<dim3(EE / 64, (NB * SS) / 64), blk, 0, stream>>>(
      xh, xm, wvh, wvm, bv, vws);

  attn_topk<<<dim3(NBH * (SS / 16)), dim3(512), 0, stream>>>(
      qh, qm, ql, kh, km, kl, vws, ath, atm);

  // O: 64x64 tile, grid (16, 32) = 512 blocks (2/CU)
  gemm_nl2<2><<<dim3(EE / 64, (NB * SS) / 64), blk, 0, stream>>>(
      ath, atm, woh, wom, bo, (float*)d_out);
}

// Round 13
// 337.206 us; speedup vs baseline: 1.1817x; 1.0181x over previous
//
#include <hip/hip_runtime.h>
#include <hip/hip_bf16.h>
#include <stdint.h>

// DynamicSparseAttention MI355X r21 — fp32 I/O.
// History: r9 @322. r10/r16/r19 spill fails. r11-r13 block-config fails
// (occupancy pinned ~14 waves/CU). r14 @317.3 (wave-independent tail).
// r17 @313.9 (+setprio T5). r18 @313.8 BEST (attn 137.3). r20 fixed-64 rank
// loop: +33us (MORE work, not less latency — selection is at its floor).
// r21: attn reverted to r18-EXACT. V-projection FUSED into the Q/K GEMM as
// blockIdx.z==2 (grid (16,16,3)=768, XCD remap bijective): V is independent
// of Q/K, so its 256 blocks co-schedule with Q/K's 512 in one dispatch
// (3 blocks/CU mixed-phase, fills barrier-drain stalls) and one launch gap
// disappears. z<2 path bit-identical; z=2 path = gemm_nl2<1>'s exact product
// order (hh k-split, hm, mh) -> bit-identical V. o-proj unchanged.

typedef __bf16 bf16_t;
typedef bf16_t bf16x8 __attribute__((ext_vector_type(8)));
typedef bf16_t bf16x4 __attribute__((ext_vector_type(4)));
typedef float  f32x4  __attribute__((ext_vector_type(4)));

#define NB 2
#define SS 1024
#define EE 1024
#define NH 16
#define HD 64
#define NBH (NB*NH)
#define NX_ ((size_t)NB*SS*EE)   // 2,097,152
#define NW_ ((size_t)EE*EE)      // 1,048,576

__device__ __forceinline__ f32x4 mfma16(bf16x8 a, bf16x8 b, f32x4 c) {
  return __builtin_amdgcn_mfma_f32_16x16x32_bf16(a, b, c, 0, 0, 0);
}

__device__ __forceinline__ void split3(float x, bf16_t& h, bf16_t& m, bf16_t& l) {
  h = (bf16_t)x;
  float r = x - (float)h;     // exact
  m = (bf16_t)r;
  float r2 = r - (float)m;    // exact
  l = (bf16_t)r2;             // residual <= 2^-27 |x|
}

// wave-local LDS ordering fence (per-wave scratch; no cross-wave deps)
__device__ __forceinline__ void wave_fence() {
  __builtin_amdgcn_wave_barrier();
  __builtin_amdgcn_s_waitcnt(0);
  __builtin_amdgcn_wave_barrier();
}

// async global->LDS, 16B per lane; LDS dest = wave-uniform base + lane*16
__device__ __forceinline__ void gld16(const bf16_t* g, bf16_t* l) {
  __builtin_amdgcn_global_load_lds(
      (const __attribute__((address_space(1))) void*)g,
      (__attribute__((address_space(3))) void*)l, 16, 0, 0);
}

// ---------------------------------------------------------------------------
// fused presplit of x, Wq, Wk, Wv, Wo into h/m/l limb arrays (unchanged)
// ---------------------------------------------------------------------------
__global__ __launch_bounds__(256) void presplit_all(
    const float* __restrict__ x,  const float* __restrict__ wq,
    const float* __restrict__ wk, const float* __restrict__ wv,
    const float* __restrict__ wo, bf16_t* __restrict__ base)
{
  const int blk = blockIdx.x;
  const float* src; bf16_t* h; size_t n; int i;
  if (blk < 2048)      { src = x;  h = base;                   n = NX_; i = blk;        }
  else if (blk < 3072) { src = wq; h = base + 3*NX_;           n = NW_; i = blk - 2048; }
  else if (blk < 4096) { src = wk; h = base + 3*NX_ + 3*NW_;   n = NW_; i = blk - 3072; }
  else if (blk < 5120) { src = wv; h = base + 3*NX_ + 6*NW_;   n = NW_; i = blk - 4096; }
  else                 { src = wo; h = base + 3*NX_ + 9*NW_;   n = NW_; i = blk - 5120; }
  bf16_t* m = h + n;
  bf16_t* l = m + n;
  int idx = i * 256 + threadIdx.x;            // float4 index
  float4 v = ((const float4*)src)[idx];
  float t[4] = { v.x, v.y, v.z, v.w };
  bf16x4 hv, mv, lv;
#pragma unroll
  for (int j = 0; j < 4; j++) {
    bf16_t a, b, c;
    split3(t[j], a, b, c);
    hv[j] = a; mv[j] = b; lv[j] = c;
  }
  ((bf16x4*)h)[idx] = hv;
  ((bf16x4*)m)[idx] = mv;
  ((bf16x4*)l)[idx] = lv;
}

// ---------------------------------------------------------------------------
// Fused Q+K+V projection GEMM, 128x64 tile. grid (16, 16, 3) = 768 blocks.
// z=0: Wq->q limbs, z=1: Wk->k limbs (6 products, bit-identical to r18's
// gemm_qk). z=2: Wv->vws fp32 (hh k-split + hm + mh, bit-identical to
// gemm_nl2<1>). XCD-contiguous swizzle (bijective: 768%8==0).
// ---------------------------------------------------------------------------
__global__ __launch_bounds__(256, 2) void gemm_qkv(
    const bf16_t* __restrict__ Ah, const bf16_t* __restrict__ Am,
    const bf16_t* __restrict__ Al,
    const bf16_t* __restrict__ Bqh, const bf16_t* __restrict__ Bqm,
    const bf16_t* __restrict__ Bql,
    const bf16_t* __restrict__ Bkh, const bf16_t* __restrict__ Bkm,
    const bf16_t* __restrict__ Bkl,
    const bf16_t* __restrict__ Bvh, const bf16_t* __restrict__ Bvm,
    const float* __restrict__ biasq, const float* __restrict__ biask,
    const float* __restrict__ biasv,
    bf16_t* __restrict__ qH, bf16_t* __restrict__ qM, bf16_t* __restrict__ qL,
    bf16_t* __restrict__ kH, bf16_t* __restrict__ kM, bf16_t* __restrict__ kL,
    float* __restrict__ vF)
{
  __shared__ bf16_t As[3][128 * 32];   // row-major, unpadded (gld16 lane order)
  __shared__ bf16_t Bs[3][64 * 32];

  // XCD-contiguous remap (bijective on [0,768); 768%8==0, 768/8=96)
  const int flat = blockIdx.x + 16 * blockIdx.y + 256 * blockIdx.z;
  const int eff  = (flat & 7) * 96 + (flat >> 3);
  const int z  = eff >> 8;             // 0,1,2
  const int bx = eff & 15, by = (eff >> 4) & 15;

  const bf16_t* AP[3] = { Ah, Am, Al };
  const bf16_t* BP[3] = { z == 0 ? Bqh : (z == 1 ? Bkh : Bvh),
                          z == 0 ? Bqm : (z == 1 ? Bkm : Bvm),
                          z == 0 ? Bql : (z == 1 ? Bkl : Bvm) };  // [2] unused @z=2
  const float* bias = z == 0 ? biasq : (z == 1 ? biask : biasv);
  bf16_t* dH = z ? kH : qH;            // unused @z=2
  bf16_t* dM = z ? kM : qM;
  bf16_t* dL = z ? kL : qL;

  const int tid  = threadIdx.x;
  const int wv   = tid >> 6, lane = tid & 63;
  const int quad = lane >> 4, l16 = lane & 15;
  const int m0 = by * 128, n0 = bx * 64;
  const int wm = (wv & 1) * 64, wn = (wv >> 1) * 32;

  // staging: A rows [wv*32, wv*32+32) via two gld16; B rows [wv*16, wv*16+16)
  const int arow = wv * 32 + (lane >> 2);
  const int brow = wv * 16 + (lane >> 2);
  const int q8   = (lane & 3) * 8;
  const size_t aoff0 = (size_t)(m0 + arow) * 1024 + q8;
  const size_t boff  = (size_t)(n0 + brow) * 1024 + q8;

  const int NL = (z < 2) ? 3 : 2;      // limbs staged (block-uniform)

  f32x4 accH0[4][2] = {};   // hh, k < 512
  f32x4 accH1[4][2] = {};   // hh, k >= 512
  f32x4 accC [4][2] = {};   // corrections (small magnitude)

  for (int k0 = 0; k0 < 1024; k0 += 32) {
    __syncthreads();                     // previous iter's frags consumed
    for (int L = 0; L < NL; L++) {
      gld16(AP[L] + aoff0 + k0,              &As[L][(wv * 32) * 32]);
      gld16(AP[L] + aoff0 + 16 * 1024 + k0,  &As[L][(wv * 32 + 16) * 32]);
      gld16(BP[L] + boff + k0,               &Bs[L][(wv * 16) * 32]);
    }
    __syncthreads();                     // staging visible

    bf16x8 bfr[2][3];
#pragma unroll
    for (int nt = 0; nt < 2; nt++)
#pragma unroll
      for (int L = 0; L < 3; L++)
        bfr[nt][L] = *(const bf16x8*)&Bs[L][(wn + nt * 16 + l16) * 32 + quad * 8];

    const bool hi = (k0 >= 512);
#pragma unroll
    for (int mt = 0; mt < 4; mt++) {
      bf16x8 af[3];
#pragma unroll
      for (int L = 0; L < 3; L++)
        af[L] = *(const bf16x8*)&As[L][(wm + mt * 16 + l16) * 32 + quad * 8];
#pragma unroll
      for (int nt = 0; nt < 2; nt++) {
        f32x4& H = hi ? accH1[mt][nt] : accH0[mt][nt];
        H = mfma16(af[0], bfr[nt][0], H);                      // hh
        f32x4 c = accC[mt][nt];
        c = mfma16(af[0], bfr[nt][1], c);                      // hm
        c = mfma16(af[1], bfr[nt][0], c);                      // mh
        if (z < 2) {
          c = mfma16(af[0], bfr[nt][2], c);                    // hl
          c = mfma16(af[2], bfr[nt][0], c);                    // lh
          c = mfma16(af[1], bfr[nt][1], c);                    // mm
        }
        accC[mt][nt] = c;
      }
    }
  }

  // epilogue: D[row=quad*4+r][col=l16]
#pragma unroll
  for (int mt = 0; mt < 4; mt++)
#pragma unroll
  for (int nt = 0; nt < 2; nt++)
#pragma unroll
  for (int r  = 0; r  < 4;  r++) {
    int gm = m0 + wm + mt * 16 + quad * 4 + r;
    int gn = n0 + wn + nt * 16 + l16;
    float v = (accH0[mt][nt][r] + accH1[mt][nt][r]) + accC[mt][nt][r] + bias[gn];
    int b_ = gm >> 10, s_ = gm & 1023, h_ = gn >> 6, d_ = gn & 63;
    size_t di = (((size_t)b_ * NH + h_) * SS + s_) * HD + d_;
    if (z < 2) {
      bf16_t hh, mm, ll;
      split3(v, hh, mm, ll);
      dH[di] = hh; dM[di] = mm; dL[di] = ll;
    } else {
      vF[di] = v;
    }
  }
}

// ---------------------------------------------------------------------------
// 3-product NT GEMM (hh k-split + hm/mh corrections), 64x64 tile, grid (16,32).
// MODE 2: fp32 row-major [M,N] (o-proj). XCD-contiguous swizzle (r18).
// ---------------------------------------------------------------------------
template<int MODE>
__global__ __launch_bounds__(256, 4) void gemm_nl2(
    const bf16_t* __restrict__ Ah, const bf16_t* __restrict__ Am,
    const bf16_t* __restrict__ Bh, const bf16_t* __restrict__ Bm,
    const float* __restrict__ bias, float* __restrict__ dF)
{
  __shared__ bf16_t As[2][64 * 32];
  __shared__ bf16_t Bs[2][64 * 32];

  const bf16_t* AP[2] = { Ah, Am };
  const bf16_t* BP[2] = { Bh, Bm };

  // XCD-contiguous remap (bijective on [0,512))
  const int flat = blockIdx.x + 16 * blockIdx.y;
  const int eff  = (flat & 7) * 64 + (flat >> 3);
  const int bx = eff & 15, by = eff >> 4;

  const int tid  = threadIdx.x;
  const int wv   = tid >> 6, lane = tid & 63;
  const int quad = lane >> 4, l16 = lane & 15;
  const int m0 = by * 64, n0 = bx * 64;
  const int wm = (wv & 1) * 32, wn = (wv >> 1) * 32;

  const int srow = wv * 16 + (lane >> 2);
  const int q8   = (lane & 3) * 8;
  const size_t aoff = (size_t)(m0 + srow) * 1024 + q8;
  const size_t boff = (size_t)(n0 + srow) * 1024 + q8;

  f32x4 accH0[2][2] = {};
  f32x4 accH1[2][2] = {};
  f32x4 accC [2][2] = {};

  for (int k0 = 0; k0 < 1024; k0 += 32) {
    __syncthreads();
#pragma unroll
    for (int L = 0; L < 2; L++) {
      gld16(AP[L] + aoff + k0, &As[L][(wv * 16) * 32]);
      gld16(BP[L] + boff + k0, &Bs[L][(wv * 16) * 32]);
    }
    __syncthreads();

    bf16x8 bfr[2][2];
#pragma unroll
    for (int nt = 0; nt < 2; nt++)
#pragma unroll
      for (int L = 0; L < 2; L++)
        bfr[nt][L] = *(const bf16x8*)&Bs[L][(wn + nt * 16 + l16) * 32 + quad * 8];

    const bool hi = (k0 >= 512);
#pragma unroll
    for (int mt = 0; mt < 2; mt++) {
      bf16x8 af[2];
#pragma unroll
      for (int L = 0; L < 2; L++)
        af[L] = *(const bf16x8*)&As[L][(wm + mt * 16 + l16) * 32 + quad * 8];
#pragma unroll
      for (int nt = 0; nt < 2; nt++) {
        f32x4& H = hi ? accH1[mt][nt] : accH0[mt][nt];
        H = mfma16(af[0], bfr[nt][0], H);                      // hh
        f32x4 c = accC[mt][nt];
        c = mfma16(af[0], bfr[nt][1], c);                      // hm
        c = mfma16(af[1], bfr[nt][0], c);                      // mh
        accC[mt][nt] = c;
      }
    }
  }

#pragma unroll
  for (int mt = 0; mt < 2; mt++)
#pragma unroll
  for (int nt = 0; nt < 2; nt++)
#pragma unroll
  for (int r  = 0; r  < 4;  r++) {
    int gm = m0 + wm + mt * 16 + quad * 4 + r;
    int gn = n0 + wn + nt * 16 + l16;
    float v = (accH0[mt][nt][r] + accH1[mt][nt][r]) + accC[mt][nt][r] + bias[gn];
    if (MODE == 2) {
      dF[(size_t)gm * 1024 + gn] = v;
    } else {
      int b_ = gm >> 10, s_ = gm & 1023, h_ = gn >> 6, d_ = gn & 63;
      dF[(((size_t)b_ * NH + h_) * SS + s_) * HD + d_] = v;
    }
  }
}

// ---------------------------------------------------------------------------
// Fused attention (r18-EXACT): one (b,h) x 16 queries, 512 thr / 8 waves.
// Score: single-chunk 16x1028 transpose, wave wv covers keys [wv*128,+128),
// r9-exact accumulation, s_setprio(1) around each t2's 12-MFMA cluster.
// ONE block barrier. Tail wave-independent (queries 2wv, 2wv+1; bins row
// 2wv, selW/selI row 2wv+1; runtime-C rank loop). PV wave-local, 32-deep.
// ---------------------------------------------------------------------------
__global__ __launch_bounds__(512, 4) void attn_topk(
    const bf16_t* __restrict__ qhg, const bf16_t* __restrict__ qmg,
    const bf16_t* __restrict__ qlg,
    const bf16_t* __restrict__ khg, const bf16_t* __restrict__ kmg,
    const bf16_t* __restrict__ klg,
    const float*  __restrict__ vg,
    bf16_t* __restrict__ attnH, bf16_t* __restrict__ attnM)
{
  __shared__ float sc[16 * 1028];       // scores; rows become per-wave scratch

  const int tid  = threadIdx.x;
  const int wv   = tid >> 6, lane = tid & 63;
  const int quad = lane >> 4, l16 = lane & 15;
  const int xcd = blockIdx.x & 7;
  const int g   = blockIdx.x >> 3;        // 0..255
  const int bh  = xcd + 8 * (g >> 6);     // 0..31 (bh pinned to XCD)
  const int qt  = g & 63;
  const int b_ = bh >> 4, h_ = bh & 15;
  const int q0 = qt * 16;

  // A-frags direct from global: lane holds q[m=l16][k=quad*8+j]
  const size_t qbase = ((size_t)bh * SS + q0 + l16) * HD + quad * 8;
  bf16x8 aH[2], aM[2], aL[2];
#pragma unroll
  for (int ks = 0; ks < 2; ks++) {
    aH[ks] = *(const bf16x8*)(qhg + qbase + ks * 32);
    aM[ks] = *(const bf16x8*)(qmg + qbase + ks * 32);
    aL[ks] = *(const bf16x8*)(qlg + qbase + ks * 32);
  }

  // ---- score phase: wave wv covers keys [wv*128, wv*128+128) — r9-exact ----
  const size_t kwb = ((size_t)bh * SS + wv * 128 + l16) * HD + quad * 8;
#pragma unroll 4
  for (int t2 = 0; t2 < 8; t2++) {
    const size_t kb = kwb + (size_t)t2 * 16 * HD;
    bf16x8 bH0 = *(const bf16x8*)(khg + kb);
    bf16x8 bH1 = *(const bf16x8*)(khg + kb + 32);
    bf16x8 bM0 = *(const bf16x8*)(kmg + kb);
    bf16x8 bM1 = *(const bf16x8*)(kmg + kb + 32);
    bf16x8 bL0 = *(const bf16x8*)(klg + kb);
    bf16x8 bL1 = *(const bf16x8*)(klg + kb + 32);
    f32x4 accA = {}, accB = {}, accC = {};
    __builtin_amdgcn_s_setprio(1);               // T5: favor MFMA-issuing wave
    accA = mfma16(aH[0], bH0, accA);             // hh, k-half 0
    accB = mfma16(aH[1], bH1, accB);             // hh, k-half 1
    accC = mfma16(aH[0], bM0, accC);             // hm
    accC = mfma16(aH[1], bM1, accC);
    accC = mfma16(aM[0], bH0, accC);             // mh
    accC = mfma16(aM[1], bH1, accC);
    accC = mfma16(aH[0], bL0, accC);             // hl
    accC = mfma16(aH[1], bL1, accC);
    accC = mfma16(aL[0], bH0, accC);             // lh
    accC = mfma16(aL[1], bH1, accC);
    accC = mfma16(aM[0], bM0, accC);             // mm
    accC = mfma16(aM[1], bM1, accC);
    __builtin_amdgcn_s_setprio(0);
    int key = wv * 128 + t2 * 16 + l16;
#pragma unroll
    for (int r = 0; r < 4; r++)
      sc[(quad * 4 + r) * 1028 + key] = ((accA[r] + accB[r]) + accC[r]) * 0.125f;
  }
  __syncthreads();                        // the ONLY block barrier

  // ---- wave wv owns queries 2wv, 2wv+1 (sc rows 2wv, 2wv+1) ----
  float fv[2][16];
#pragma unroll
  for (int i = 0; i < 16; i++) {
    fv[0][i] = sc[(2 * wv)     * 1028 + i * 64 + lane];
    fv[1][i] = sc[(2 * wv + 1) * 1028 + i * 64 + lane];
  }
  wave_fence();                           // row reads done before overlay

  // wave-owned scratch INSIDE the wave's own rows (no other wave touches them)
  uint32_t* bins  = (uint32_t*)(sc + (2 * wv) * 1028);   // 512 u32 (<=1028 fl)
  float*    candV = (float*)bins;                        // reuse after scan
  ushort*   candI = (ushort*)(bins + 64);
  float*    selWw = sc + (2 * wv + 1) * 1028;            // 128 floats
  ushort*   selIw = (ushort*)(selWw + 128);              // 128 u16

  const uint64_t lt = (1ull << lane) - 1ull;
  for (int qi = 0; qi < 2; qi++) {
    const float* fq = fv[qi];
    // zero bins (512 u32 per wave)
    *(uint4*)(bins + lane * 8)     = uint4{0, 0, 0, 0};
    *(uint4*)(bins + lane * 8 + 4) = uint4{0, 0, 0, 0};
    wave_fence();
    // histogram: bin = clamp((int)(f*32+256), 0, 511) — monotone in f
#pragma unroll
    for (int i = 0; i < 16; i++) {
      int b = (int)fmaxf(0.f, fminf(511.f, fmaf(fq[i], 32.f, 256.f)));
      atomicAdd(bins + b, 1u);
    }
    wave_fence();
    // descending scan: lane covers bins [504-8*lane, 511-8*lane]
    int base = 504 - 8 * lane;
    uint4 h0 = *(const uint4*)(bins + base);
    uint4 h1 = *(const uint4*)(bins + base + 4);
    uint32_t s_l = h0.x + h0.y + h0.z + h0.w + h1.x + h1.y + h1.z + h1.w;
    uint32_t x = s_l;
#pragma unroll
    for (int off = 1; off < 64; off <<= 1) {
      uint32_t y = __shfl_up(x, off);
      if (lane >= off) x += y;
    }
    uint32_t P = x - s_l;               // count in bins strictly above lane's range
    uint32_t harr[8] = { h1.w, h1.z, h1.y, h1.x, h0.w, h0.z, h0.y, h0.x };
    uint32_t cb = P, G = 0;
    int foundc = -1;
#pragma unroll
    for (int c = 0; c < 8; c++) {
      uint32_t hc = harr[c];
      if (foundc < 0 && (int)cb < 64 && (int)(cb + hc) >= 64) { foundc = c; G = cb; }
      cb += hc;
    }
    uint64_t fm = __ballot(foundc >= 0);
    int src   = __ffsll((unsigned long long)fm) - 1;
    int Bstar = __shfl((foundc >= 0) ? (511 - 8 * lane - foundc) : 0, src);
    int Gs    = __shfl((int)G, src);
    int needed = 64 - Gs;
    wave_fence();                        // scan reads done before candV writes

    // pass 1: bin > Bstar -> selected (Gs total), slots [0, Gs)
    int pos = 0, cT = 0;
#pragma unroll
    for (int i = 0; i < 16; i++) {
      int b = (int)fmaxf(0.f, fminf(511.f, fmaf(fq[i], 32.f, 256.f)));
      bool hi = b > Bstar;
      bool cd = (b == Bstar);
      uint64_t hm = __ballot(hi);
      uint64_t em = __ballot(cd);
      int p  = pos + (int)__popcll(hm & lt);
      int cp = cT  + (int)__popcll(em & lt);
      if (hi) { selWw[qi * 64 + p] = fq[i]; selIw[qi * 64 + p] = (ushort)(i * 64 + lane); }
      if (cd && cp < 64) { candV[cp] = fq[i]; candI[cp] = (ushort)(i * 64 + lane); }
      pos += (int)__popcll(hm);
      cT  += (int)__popcll(em);
    }
    wave_fence();
    // exact ranking inside boundary bin (value desc, index asc)
    int C = cT < 64 ? cT : 64;
    float mv = candV[lane];
    int   mi = candI[lane];
    int rank = 0;
    for (int i = 0; i < C; i++) {        // LDS broadcast reads
      float ov = candV[i]; int oi = candI[i];
      rank += (ov > mv || (ov == mv && oi < mi)) ? 1 : 0;
    }
    bool take = (lane < C) && (rank < needed);
    uint64_t tm = __ballot(take);
    int slot = Gs + (int)__popcll(tm & lt);
    if (take) { selWw[qi * 64 + slot] = mv; selIw[qi * 64 + slot] = (ushort)mi; }
    wave_fence();
    // softmax over the 64 selected scores
    float sv = selWw[qi * 64 + lane];
    float mx = sv;
#pragma unroll
    for (int off = 32; off >= 1; off >>= 1) mx = fmaxf(mx, __shfl_xor(mx, off));
    float e = __expf(sv - mx);
    float sum = e;
#pragma unroll
    for (int off = 32; off >= 1; off >>= 1) sum += __shfl_xor(sum, off);
    selWw[qi * 64 + lane] = e / sum;
    wave_fence();
  }
  // NO block barrier: PV consumes this wave's own selW/selI only.

  // ---- PV (wave-local): lane -> ql = lane>>5, jh = (lane>>4)&1,
  //      d-block = (lane&15)*4. 32-deep batched gather prefetch.
  {
    int ql = lane >> 5, jh = (lane >> 4) & 1, dblk = (lane & 15) * 4;
    const float* vb = vg + (size_t)bh * SS * HD;
    f32x4 a4 = {};
    float wreg[32]; int ireg[32];
#pragma unroll
    for (int j = 0; j < 32; j++) {
      int jj = jh * 32 + j;
      wreg[j] = selWw[ql * 64 + jj];
      ireg[j] = selIw[ql * 64 + jj];
    }
#pragma unroll
    for (int j = 0; j < 32; j++) {
      f32x4 v4 = *(const f32x4*)(vb + (size_t)ireg[j] * HD + dblk);
      a4 += wreg[j] * v4;
    }
#pragma unroll
    for (int c = 0; c < 4; c++) a4[c] += __shfl_xor(a4[c], 16);
    if (jh == 0) {
      int qg = q0 + 2 * wv + ql;
      size_t dofs = ((size_t)b_ * SS + qg) * EE + h_ * HD + dblk;
      bf16x4 oh, om;
#pragma unroll
      for (int j = 0; j < 4; j++) {
        bf16_t hh = (bf16_t)a4[j];
        oh[j] = hh;
        om[j] = (bf16_t)(a4[j] - (float)hh);
      }
      *(bf16x4*)(attnH + dofs) = oh;
      *(bf16x4*)(attnM + dofs) = om;
    }
  }
}

// ---------------------------------------------------------------------------
extern "C" void kernel_launch(void* const* d_in, const int* in_sizes, int n_in,
                              void* d_out, int out_size, void* d_ws, size_t ws_size,
                              hipStream_t stream)
{
  const float* x  = (const float*)d_in[0];
  const float* Wq = (const float*)d_in[1];
  const float* bq = (const float*)d_in[2];
  const float* Wk = (const float*)d_in[3];
  const float* bk = (const float*)d_in[4];
  const float* Wv = (const float*)d_in[5];
  const float* bv = (const float*)d_in[6];
  const float* Wo = (const float*)d_in[7];
  const float* bo = (const float*)d_in[8];

  bf16_t* base = (bf16_t*)d_ws;
  bf16_t *xh = base,            *xm = xh + NX_,  *xl = xm + NX_;
  bf16_t *wqh = base + 3*NX_,           *wqm = wqh + NW_, *wql = wqm + NW_;
  bf16_t *wkh = base + 3*NX_ + 3*NW_,   *wkm = wkh + NW_, *wkl = wkm + NW_;
  bf16_t *wvh = base + 3*NX_ + 6*NW_,   *wvm = wvh + NW_;
  bf16_t *woh = base + 3*NX_ + 9*NW_,   *wom = woh + NW_;
  bf16_t *p2 = base + 3*NX_ + 12*NW_;
  bf16_t *qh = p2,          *qm = qh + NX_, *ql = qm + NX_;
  bf16_t *kh = ql + NX_,    *km = kh + NX_, *kl = km + NX_;
  float  *vws = (float*)(kl + NX_);
  bf16_t *ath = (bf16_t*)(vws + NX_), *atm = ath + NX_;

  dim3 blk(256);
  presplit_all<<<dim3(6144), blk, 0, stream>>>(x, Wq, Wk, Wv, Wo, base);

  // fused Q+K+V: 128x64 tile, grid (16, 16, 3) = 768 blocks (3/CU mixed)
  gemm_qkv<<<dim3(EE / 64, (NB * SS) / 128, 3), blk, 0, stream>>>(
      xh, xm, xl, wqh, wqm, wql, wkh, wkm, wkl, wvh, wvm,
      bq, bk, bv, qh, qm, ql, kh, km, kl, vws);

  attn_topk<<<dim3(NBH * (SS / 16)), dim3(512), 0, stream>>>(
      qh, qm, ql, kh, km, kl, vws, ath, atm);

  // O: 64x64 tile, grid (16, 32) = 512 blocks (2/CU)
  gemm_nl2<2><<<dim3(EE / 64, (NB * SS) / 64), blk, 0, stream>>>(
      ath, atm, woh, wom, bo, (float*)d_out);
}

// Round 14
// 312.415 us; speedup vs baseline: 1.2755x; 1.0793x over previous
//
#include <hip/hip_runtime.h>
#include <hip/hip_bf16.h>
#include <stdint.h>

// DynamicSparseAttention MI355X r22 — fp32 I/O. (= r18 byte-exact revert)
// History: r9 @322. r10/r16/r19 spill fails. r11-r13 block-config fails
// (occupancy pinned ~14 waves/CU). r14 @317.3 (wave-independent tail,
// 1 barrier, -5us). r15 ILP x. r17 @313.9 (+setprio T5, -5.5us).
// r18 @313.8 BEST (attn 137.3): +GEMM XCD swizzle, PV-32 (both neutral).
// r20 fixed-64 rank loop x (+33us). r21 QKV fusion x (+23us: V lost its
// 64-tile/4-per-CU shape; 768 blocks @2/CU -> half-empty second round).
// Conclusion: each kernel is at its shape optimum; r18 locked in as final.

typedef __bf16 bf16_t;
typedef bf16_t bf16x8 __attribute__((ext_vector_type(8)));
typedef bf16_t bf16x4 __attribute__((ext_vector_type(4)));
typedef float  f32x4  __attribute__((ext_vector_type(4)));

#define NB 2
#define SS 1024
#define EE 1024
#define NH 16
#define HD 64
#define NBH (NB*NH)
#define NX_ ((size_t)NB*SS*EE)   // 2,097,152
#define NW_ ((size_t)EE*EE)      // 1,048,576

__device__ __forceinline__ f32x4 mfma16(bf16x8 a, bf16x8 b, f32x4 c) {
  return __builtin_amdgcn_mfma_f32_16x16x32_bf16(a, b, c, 0, 0, 0);
}

__device__ __forceinline__ void split3(float x, bf16_t& h, bf16_t& m, bf16_t& l) {
  h = (bf16_t)x;
  float r = x - (float)h;     // exact
  m = (bf16_t)r;
  float r2 = r - (float)m;    // exact
  l = (bf16_t)r2;             // residual <= 2^-27 |x|
}

// wave-local LDS ordering fence (per-wave scratch; no cross-wave deps)
__device__ __forceinline__ void wave_fence() {
  __builtin_amdgcn_wave_barrier();
  __builtin_amdgcn_s_waitcnt(0);
  __builtin_amdgcn_wave_barrier();
}

// async global->LDS, 16B per lane; LDS dest = wave-uniform base + lane*16
__device__ __forceinline__ void gld16(const bf16_t* g, bf16_t* l) {
  __builtin_amdgcn_global_load_lds(
      (const __attribute__((address_space(1))) void*)g,
      (__attribute__((address_space(3))) void*)l, 16, 0, 0);
}

// ---------------------------------------------------------------------------
// fused presplit of x, Wq, Wk, Wv, Wo into h/m/l limb arrays (unchanged)
// ---------------------------------------------------------------------------
__global__ __launch_bounds__(256) void presplit_all(
    const float* __restrict__ x,  const float* __restrict__ wq,
    const float* __restrict__ wk, const float* __restrict__ wv,
    const float* __restrict__ wo, bf16_t* __restrict__ base)
{
  const int blk = blockIdx.x;
  const float* src; bf16_t* h; size_t n; int i;
  if (blk < 2048)      { src = x;  h = base;                   n = NX_; i = blk;        }
  else if (blk < 3072) { src = wq; h = base + 3*NX_;           n = NW_; i = blk - 2048; }
  else if (blk < 4096) { src = wk; h = base + 3*NX_ + 3*NW_;   n = NW_; i = blk - 3072; }
  else if (blk < 5120) { src = wv; h = base + 3*NX_ + 6*NW_;   n = NW_; i = blk - 4096; }
  else                 { src = wo; h = base + 3*NX_ + 9*NW_;   n = NW_; i = blk - 5120; }
  bf16_t* m = h + n;
  bf16_t* l = m + n;
  int idx = i * 256 + threadIdx.x;            // float4 index
  float4 v = ((const float4*)src)[idx];
  float t[4] = { v.x, v.y, v.z, v.w };
  bf16x4 hv, mv, lv;
#pragma unroll
  for (int j = 0; j < 4; j++) {
    bf16_t a, b, c;
    split3(t[j], a, b, c);
    hv[j] = a; mv[j] = b; lv[j] = c;
  }
  ((bf16x4*)h)[idx] = hv;
  ((bf16x4*)m)[idx] = mv;
  ((bf16x4*)l)[idx] = lv;
}

// ---------------------------------------------------------------------------
// Fused Q+K projection GEMM, 128x64 tile. grid (16, 16, 2) = 512 blocks.
// XCD-contiguous swizzle. Math unchanged from r9.
// ---------------------------------------------------------------------------
__global__ __launch_bounds__(256, 2) void gemm_qk(
    const bf16_t* __restrict__ Ah, const bf16_t* __restrict__ Am,
    const bf16_t* __restrict__ Al,
    const bf16_t* __restrict__ Bqh, const bf16_t* __restrict__ Bqm,
    const bf16_t* __restrict__ Bql,
    const bf16_t* __restrict__ Bkh, const bf16_t* __restrict__ Bkm,
    const bf16_t* __restrict__ Bkl,
    const float* __restrict__ biasq, const float* __restrict__ biask,
    bf16_t* __restrict__ qH, bf16_t* __restrict__ qM, bf16_t* __restrict__ qL,
    bf16_t* __restrict__ kH, bf16_t* __restrict__ kM, bf16_t* __restrict__ kL)
{
  __shared__ bf16_t As[3][128 * 32];   // row-major, unpadded (gld16 lane order)
  __shared__ bf16_t Bs[3][64 * 32];

  // XCD-contiguous remap (bijective on [0,512); 512%8==0)
  const int flat = blockIdx.x + 16 * blockIdx.y + 256 * blockIdx.z;
  const int eff  = (flat & 7) * 64 + (flat >> 3);
  const int bx = eff & 15, by = (eff >> 4) & 15, z = eff >> 8;

  const bf16_t* AP[3] = { Ah, Am, Al };
  const bf16_t* BP[3] = { z ? Bkh : Bqh, z ? Bkm : Bqm, z ? Bkl : Bql };
  const float* bias = z ? biask : biasq;
  bf16_t* dH = z ? kH : qH;
  bf16_t* dM = z ? kM : qM;
  bf16_t* dL = z ? kL : qL;

  const int tid  = threadIdx.x;
  const int wv   = tid >> 6, lane = tid & 63;
  const int quad = lane >> 4, l16 = lane & 15;
  const int m0 = by * 128, n0 = bx * 64;
  const int wm = (wv & 1) * 64, wn = (wv >> 1) * 32;

  // staging: A rows [wv*32, wv*32+32) via two gld16; B rows [wv*16, wv*16+16)
  const int arow = wv * 32 + (lane >> 2);
  const int brow = wv * 16 + (lane >> 2);
  const int q8   = (lane & 3) * 8;
  const size_t aoff0 = (size_t)(m0 + arow) * 1024 + q8;
  const size_t boff  = (size_t)(n0 + brow) * 1024 + q8;

  f32x4 accH0[4][2] = {};   // hh, k < 512
  f32x4 accH1[4][2] = {};   // hh, k >= 512
  f32x4 accC [4][2] = {};   // corrections (small magnitude)

  for (int k0 = 0; k0 < 1024; k0 += 32) {
    __syncthreads();                     // previous iter's frags consumed
#pragma unroll
    for (int L = 0; L < 3; L++) {
      gld16(AP[L] + aoff0 + k0,              &As[L][(wv * 32) * 32]);
      gld16(AP[L] + aoff0 + 16 * 1024 + k0,  &As[L][(wv * 32 + 16) * 32]);
      gld16(BP[L] + boff + k0,               &Bs[L][(wv * 16) * 32]);
    }
    __syncthreads();                     // staging visible

    bf16x8 bfr[2][3];
#pragma unroll
    for (int nt = 0; nt < 2; nt++)
#pragma unroll
      for (int L = 0; L < 3; L++)
        bfr[nt][L] = *(const bf16x8*)&Bs[L][(wn + nt * 16 + l16) * 32 + quad * 8];

    const bool hi = (k0 >= 512);
#pragma unroll
    for (int mt = 0; mt < 4; mt++) {
      bf16x8 af[3];
#pragma unroll
      for (int L = 0; L < 3; L++)
        af[L] = *(const bf16x8*)&As[L][(wm + mt * 16 + l16) * 32 + quad * 8];
#pragma unroll
      for (int nt = 0; nt < 2; nt++) {
        f32x4& H = hi ? accH1[mt][nt] : accH0[mt][nt];
        H = mfma16(af[0], bfr[nt][0], H);                      // hh
        f32x4 c = accC[mt][nt];
        c = mfma16(af[0], bfr[nt][1], c);                      // hm
        c = mfma16(af[1], bfr[nt][0], c);                      // mh
        c = mfma16(af[0], bfr[nt][2], c);                      // hl
        c = mfma16(af[2], bfr[nt][0], c);                      // lh
        c = mfma16(af[1], bfr[nt][1], c);                      // mm
        accC[mt][nt] = c;
      }
    }
  }

  // epilogue: D[row=quad*4+r][col=l16] -> 3-way split limbs at [B,H,S,HD]
#pragma unroll
  for (int mt = 0; mt < 4; mt++)
#pragma unroll
  for (int nt = 0; nt < 2; nt++)
#pragma unroll
  for (int r  = 0; r  < 4;  r++) {
    int gm = m0 + wm + mt * 16 + quad * 4 + r;
    int gn = n0 + wn + nt * 16 + l16;
    float v = (accH0[mt][nt][r] + accH1[mt][nt][r]) + accC[mt][nt][r] + bias[gn];
    int b_ = gm >> 10, s_ = gm & 1023, h_ = gn >> 6, d_ = gn & 63;
    size_t di = (((size_t)b_ * NH + h_) * SS + s_) * HD + d_;
    bf16_t hh, mm, ll;
    split3(v, hh, mm, ll);
    dH[di] = hh; dM[di] = mm; dL[di] = ll;
  }
}

// ---------------------------------------------------------------------------
// 3-product NT GEMM (hh k-split + hm/mh corrections), 64x64 tile, grid (16,32).
// MODE 1: fp32 [B,H,S,HD] (v-proj).  MODE 2: fp32 row-major [M,N] (o-proj).
// XCD-contiguous swizzle. Math unchanged from r8.
// ---------------------------------------------------------------------------
template<int MODE>
__global__ __launch_bounds__(256, 4) void gemm_nl2(
    const bf16_t* __restrict__ Ah, const bf16_t* __restrict__ Am,
    const bf16_t* __restrict__ Bh, const bf16_t* __restrict__ Bm,
    const float* __restrict__ bias, float* __restrict__ dF)
{
  __shared__ bf16_t As[2][64 * 32];
  __shared__ bf16_t Bs[2][64 * 32];

  const bf16_t* AP[2] = { Ah, Am };
  const bf16_t* BP[2] = { Bh, Bm };

  // XCD-contiguous remap (bijective on [0,512))
  const int flat = blockIdx.x + 16 * blockIdx.y;
  const int eff  = (flat & 7) * 64 + (flat >> 3);
  const int bx = eff & 15, by = eff >> 4;

  const int tid  = threadIdx.x;
  const int wv   = tid >> 6, lane = tid & 63;
  const int quad = lane >> 4, l16 = lane & 15;
  const int m0 = by * 64, n0 = bx * 64;
  const int wm = (wv & 1) * 32, wn = (wv >> 1) * 32;

  const int srow = wv * 16 + (lane >> 2);
  const int q8   = (lane & 3) * 8;
  const size_t aoff = (size_t)(m0 + srow) * 1024 + q8;
  const size_t boff = (size_t)(n0 + srow) * 1024 + q8;

  f32x4 accH0[2][2] = {};
  f32x4 accH1[2][2] = {};
  f32x4 accC [2][2] = {};

  for (int k0 = 0; k0 < 1024; k0 += 32) {
    __syncthreads();
#pragma unroll
    for (int L = 0; L < 2; L++) {
      gld16(AP[L] + aoff + k0, &As[L][(wv * 16) * 32]);
      gld16(BP[L] + boff + k0, &Bs[L][(wv * 16) * 32]);
    }
    __syncthreads();

    bf16x8 bfr[2][2];
#pragma unroll
    for (int nt = 0; nt < 2; nt++)
#pragma unroll
      for (int L = 0; L < 2; L++)
        bfr[nt][L] = *(const bf16x8*)&Bs[L][(wn + nt * 16 + l16) * 32 + quad * 8];

    const bool hi = (k0 >= 512);
#pragma unroll
    for (int mt = 0; mt < 2; mt++) {
      bf16x8 af[2];
#pragma unroll
      for (int L = 0; L < 2; L++)
        af[L] = *(const bf16x8*)&As[L][(wm + mt * 16 + l16) * 32 + quad * 8];
#pragma unroll
      for (int nt = 0; nt < 2; nt++) {
        f32x4& H = hi ? accH1[mt][nt] : accH0[mt][nt];
        H = mfma16(af[0], bfr[nt][0], H);                      // hh
        f32x4 c = accC[mt][nt];
        c = mfma16(af[0], bfr[nt][1], c);                      // hm
        c = mfma16(af[1], bfr[nt][0], c);                      // mh
        accC[mt][nt] = c;
      }
    }
  }

#pragma unroll
  for (int mt = 0; mt < 2; mt++)
#pragma unroll
  for (int nt = 0; nt < 2; nt++)
#pragma unroll
  for (int r  = 0; r  < 4;  r++) {
    int gm = m0 + wm + mt * 16 + quad * 4 + r;
    int gn = n0 + wn + nt * 16 + l16;
    float v = (accH0[mt][nt][r] + accH1[mt][nt][r]) + accC[mt][nt][r] + bias[gn];
    if (MODE == 2) {
      dF[(size_t)gm * 1024 + gn] = v;
    } else {
      int b_ = gm >> 10, s_ = gm & 1023, h_ = gn >> 6, d_ = gn & 63;
      dF[(((size_t)b_ * NH + h_) * SS + s_) * HD + d_] = v;
    }
  }
}

// ---------------------------------------------------------------------------
// Fused attention (r18-exact): one (b,h) x 16 queries, 512 thr / 8 waves.
// Score: single-chunk 16x1028 transpose, wave wv covers keys [wv*128,+128),
// r9-exact accumulation, s_setprio(1) around each t2's 12-MFMA cluster.
// ONE block barrier. Tail wave-independent: wave wv owns queries 2wv, 2wv+1;
// bins in sc row 2wv, selW/selI in row 2wv+1; runtime-C rank loop.
// PV wave-local, 32-deep batched gather.
// ---------------------------------------------------------------------------
__global__ __launch_bounds__(512, 4) void attn_topk(
    const bf16_t* __restrict__ qhg, const bf16_t* __restrict__ qmg,
    const bf16_t* __restrict__ qlg,
    const bf16_t* __restrict__ khg, const bf16_t* __restrict__ kmg,
    const bf16_t* __restrict__ klg,
    const float*  __restrict__ vg,
    bf16_t* __restrict__ attnH, bf16_t* __restrict__ attnM)
{
  __shared__ float sc[16 * 1028];       // scores; rows become per-wave scratch

  const int tid  = threadIdx.x;
  const int wv   = tid >> 6, lane = tid & 63;
  const int quad = lane >> 4, l16 = lane & 15;
  const int xcd = blockIdx.x & 7;
  const int g   = blockIdx.x >> 3;        // 0..255
  const int bh  = xcd + 8 * (g >> 6);     // 0..31 (bh pinned to XCD)
  const int qt  = g & 63;
  const int b_ = bh >> 4, h_ = bh & 15;
  const int q0 = qt * 16;

  // A-frags direct from global: lane holds q[m=l16][k=quad*8+j]
  const size_t qbase = ((size_t)bh * SS + q0 + l16) * HD + quad * 8;
  bf16x8 aH[2], aM[2], aL[2];
#pragma unroll
  for (int ks = 0; ks < 2; ks++) {
    aH[ks] = *(const bf16x8*)(qhg + qbase + ks * 32);
    aM[ks] = *(const bf16x8*)(qmg + qbase + ks * 32);
    aL[ks] = *(const bf16x8*)(qlg + qbase + ks * 32);
  }

  // ---- score phase: wave wv covers keys [wv*128, wv*128+128) — r9-exact ----
  const size_t kwb = ((size_t)bh * SS + wv * 128 + l16) * HD + quad * 8;
#pragma unroll 4
  for (int t2 = 0; t2 < 8; t2++) {
    const size_t kb = kwb + (size_t)t2 * 16 * HD;
    bf16x8 bH0 = *(const bf16x8*)(khg + kb);
    bf16x8 bH1 = *(const bf16x8*)(khg + kb + 32);
    bf16x8 bM0 = *(const bf16x8*)(kmg + kb);
    bf16x8 bM1 = *(const bf16x8*)(kmg + kb + 32);
    bf16x8 bL0 = *(const bf16x8*)(klg + kb);
    bf16x8 bL1 = *(const bf16x8*)(klg + kb + 32);
    f32x4 accA = {}, accB = {}, accC = {};
    __builtin_amdgcn_s_setprio(1);               // T5: favor MFMA-issuing wave
    accA = mfma16(aH[0], bH0, accA);             // hh, k-half 0
    accB = mfma16(aH[1], bH1, accB);             // hh, k-half 1
    accC = mfma16(aH[0], bM0, accC);             // hm
    accC = mfma16(aH[1], bM1, accC);
    accC = mfma16(aM[0], bH0, accC);             // mh
    accC = mfma16(aM[1], bH1, accC);
    accC = mfma16(aH[0], bL0, accC);             // hl
    accC = mfma16(aH[1], bL1, accC);
    accC = mfma16(aL[0], bH0, accC);             // lh
    accC = mfma16(aL[1], bH1, accC);
    accC = mfma16(aM[0], bM0, accC);             // mm
    accC = mfma16(aM[1], bM1, accC);
    __builtin_amdgcn_s_setprio(0);
    int key = wv * 128 + t2 * 16 + l16;
#pragma unroll
    for (int r = 0; r < 4; r++)
      sc[(quad * 4 + r) * 1028 + key] = ((accA[r] + accB[r]) + accC[r]) * 0.125f;
  }
  __syncthreads();                        // the ONLY block barrier

  // ---- wave wv owns queries 2wv, 2wv+1 (sc rows 2wv, 2wv+1) ----
  float fv[2][16];
#pragma unroll
  for (int i = 0; i < 16; i++) {
    fv[0][i] = sc[(2 * wv)     * 1028 + i * 64 + lane];
    fv[1][i] = sc[(2 * wv + 1) * 1028 + i * 64 + lane];
  }
  wave_fence();                           // row reads done before overlay

  // wave-owned scratch INSIDE the wave's own rows (no other wave touches them)
  uint32_t* bins  = (uint32_t*)(sc + (2 * wv) * 1028);   // 512 u32 (<=1028 fl)
  float*    candV = (float*)bins;                        // reuse after scan
  ushort*   candI = (ushort*)(bins + 64);
  float*    selWw = sc + (2 * wv + 1) * 1028;            // 128 floats
  ushort*   selIw = (ushort*)(selWw + 128);              // 128 u16

  const uint64_t lt = (1ull << lane) - 1ull;
  for (int qi = 0; qi < 2; qi++) {
    const float* fq = fv[qi];
    // zero bins (512 u32 per wave)
    *(uint4*)(bins + lane * 8)     = uint4{0, 0, 0, 0};
    *(uint4*)(bins + lane * 8 + 4) = uint4{0, 0, 0, 0};
    wave_fence();
    // histogram: bin = clamp((int)(f*32+256), 0, 511) — monotone in f
#pragma unroll
    for (int i = 0; i < 16; i++) {
      int b = (int)fmaxf(0.f, fminf(511.f, fmaf(fq[i], 32.f, 256.f)));
      atomicAdd(bins + b, 1u);
    }
    wave_fence();
    // descending scan: lane covers bins [504-8*lane, 511-8*lane]
    int base = 504 - 8 * lane;
    uint4 h0 = *(const uint4*)(bins + base);
    uint4 h1 = *(const uint4*)(bins + base + 4);
    uint32_t s_l = h0.x + h0.y + h0.z + h0.w + h1.x + h1.y + h1.z + h1.w;
    uint32_t x = s_l;
#pragma unroll
    for (int off = 1; off < 64; off <<= 1) {
      uint32_t y = __shfl_up(x, off);
      if (lane >= off) x += y;
    }
    uint32_t P = x - s_l;               // count in bins strictly above lane's range
    uint32_t harr[8] = { h1.w, h1.z, h1.y, h1.x, h0.w, h0.z, h0.y, h0.x };
    uint32_t cb = P, G = 0;
    int foundc = -1;
#pragma unroll
    for (int c = 0; c < 8; c++) {
      uint32_t hc = harr[c];
      if (foundc < 0 && (int)cb < 64 && (int)(cb + hc) >= 64) { foundc = c; G = cb; }
      cb += hc;
    }
    uint64_t fm = __ballot(foundc >= 0);
    int src   = __ffsll((unsigned long long)fm) - 1;
    int Bstar = __shfl((foundc >= 0) ? (511 - 8 * lane - foundc) : 0, src);
    int Gs    = __shfl((int)G, src);
    int needed = 64 - Gs;
    wave_fence();                        // scan reads done before candV writes

    // pass 1: bin > Bstar -> selected (Gs total), slots [0, Gs)
    int pos = 0, cT = 0;
#pragma unroll
    for (int i = 0; i < 16; i++) {
      int b = (int)fmaxf(0.f, fminf(511.f, fmaf(fq[i], 32.f, 256.f)));
      bool hi = b > Bstar;
      bool cd = (b == Bstar);
      uint64_t hm = __ballot(hi);
      uint64_t em = __ballot(cd);
      int p  = pos + (int)__popcll(hm & lt);
      int cp = cT  + (int)__popcll(em & lt);
      if (hi) { selWw[qi * 64 + p] = fq[i]; selIw[qi * 64 + p] = (ushort)(i * 64 + lane); }
      if (cd && cp < 64) { candV[cp] = fq[i]; candI[cp] = (ushort)(i * 64 + lane); }
      pos += (int)__popcll(hm);
      cT  += (int)__popcll(em);
    }
    wave_fence();
    // exact ranking inside boundary bin (value desc, index asc)
    int C = cT < 64 ? cT : 64;
    float mv = candV[lane];
    int   mi = candI[lane];
    int rank = 0;
    for (int i = 0; i < C; i++) {        // LDS broadcast reads
      float ov = candV[i]; int oi = candI[i];
      rank += (ov > mv || (ov == mv && oi < mi)) ? 1 : 0;
    }
    bool take = (lane < C) && (rank < needed);
    uint64_t tm = __ballot(take);
    int slot = Gs + (int)__popcll(tm & lt);
    if (take) { selWw[qi * 64 + slot] = mv; selIw[qi * 64 + slot] = (ushort)mi; }
    wave_fence();
    // softmax over the 64 selected scores
    float sv = selWw[qi * 64 + lane];
    float mx = sv;
#pragma unroll
    for (int off = 32; off >= 1; off >>= 1) mx = fmaxf(mx, __shfl_xor(mx, off));
    float e = __expf(sv - mx);
    float sum = e;
#pragma unroll
    for (int off = 32; off >= 1; off >>= 1) sum += __shfl_xor(sum, off);
    selWw[qi * 64 + lane] = e / sum;
    wave_fence();
  }
  // NO block barrier: PV consumes this wave's own selW/selI only.

  // ---- PV (wave-local): lane -> ql = lane>>5, jh = (lane>>4)&1,
  //      d-block = (lane&15)*4. 32-deep batched gather prefetch.
  {
    int ql = lane >> 5, jh = (lane >> 4) & 1, dblk = (lane & 15) * 4;
    const float* vb = vg + (size_t)bh * SS * HD;
    f32x4 a4 = {};
    float wreg[32]; int ireg[32];
#pragma unroll
    for (int j = 0; j < 32; j++) {
      int jj = jh * 32 + j;
      wreg[j] = selWw[ql * 64 + jj];
      ireg[j] = selIw[ql * 64 + jj];
    }
#pragma unroll
    for (int j = 0; j < 32; j++) {
      f32x4 v4 = *(const f32x4*)(vb + (size_t)ireg[j] * HD + dblk);
      a4 += wreg[j] * v4;
    }
#pragma unroll
    for (int c = 0; c < 4; c++) a4[c] += __shfl_xor(a4[c], 16);
    if (jh == 0) {
      int qg = q0 + 2 * wv + ql;
      size_t dofs = ((size_t)b_ * SS + qg) * EE + h_ * HD + dblk;
      bf16x4 oh, om;
#pragma unroll
      for (int j = 0; j < 4; j++) {
        bf16_t hh = (bf16_t)a4[j];
        oh[j] = hh;
        om[j] = (bf16_t)(a4[j] - (float)hh);
      }
      *(bf16x4*)(attnH + dofs) = oh;
      *(bf16x4*)(attnM + dofs) = om;
    }
  }
}

// ---------------------------------------------------------------------------
extern "C" void kernel_launch(void* const* d_in, const int* in_sizes, int n_in,
                              void* d_out, int out_size, void* d_ws, size_t ws_size,
                              hipStream_t stream)
{
  const float* x  = (const float*)d_in[0];
  const float* Wq = (const float*)d_in[1];
  const float* bq = (const float*)d_in[2];
  const float* Wk = (const float*)d_in[3];
  const float* bk = (const float*)d_in[4];
  const float* Wv = (const float*)d_in[5];
  const float* bv = (const float*)d_in[6];
  const float* Wo = (const float*)d_in[7];
  const float* bo = (const float*)d_in[8];

  bf16_t* base = (bf16_t*)d_ws;
  bf16_t *xh = base,            *xm = xh + NX_,  *xl = xm + NX_;
  bf16_t *wqh = base + 3*NX_,           *wqm = wqh + NW_, *wql = wqm + NW_;
  bf16_t *wkh = base + 3*NX_ + 3*NW_,   *wkm = wkh + NW_, *wkl = wkm + NW_;
  bf16_t *wvh = base + 3*NX_ + 6*NW_,   *wvm = wvh + NW_;
  bf16_t *woh = base + 3*NX_ + 9*NW_,   *wom = woh + NW_;
  bf16_t *p2 = base + 3*NX_ + 12*NW_;
  bf16_t *qh = p2,          *qm = qh + NX_, *ql = qm + NX_;
  bf16_t *kh = ql + NX_,    *km = kh + NX_, *kl = km + NX_;
  float  *vws = (float*)(kl + NX_);
  bf16_t *ath = (bf16_t*)(vws + NX_), *atm = ath + NX_;

  dim3 blk(256);
  presplit_all<<<dim3(6144), blk, 0, stream>>>(x, Wq, Wk, Wv, Wo, base);

  // fused Q+K: 128x64 tile, grid (16, 16, 2) = 512 blocks (2/CU)
  gemm_qk<<<dim3(EE / 64, (NB * SS) / 128, 2), blk, 0, stream>>>(
      xh, xm, xl, wqh, wqm, wql, wkh, wkm, wkl, bq, bk,
      qh, qm, ql, kh, km, kl);

  // V: 64x64 tile, grid (16, 32) = 512 blocks (2/CU)
  gemm_nl2<1><<<dim3(EE / 64, (NB * SS) / 64), blk, 0, stream>>>(
      xh, xm, wvh, wvm, bv, vws);

  attn_topk<<<dim3(NBH * (SS / 16)), dim3(512), 0, stream>>>(
      qh, qm, ql, kh, km, kl, vws, ath, atm);

  // O: 64x64 tile, grid (16, 32) = 512 blocks (2/CU)
  gemm_nl2<2><<<dim3(EE / 64, (NB * SS) / 64), blk, 0, stream>>>(
      ath, atm, woh, wom, bo, (float*)d_out);
}